// Round 8
// baseline (2517.082 us; speedup 1.0000x reference)
//
#include <hip/hip_runtime.h>
#include <math.h>

#define NB 16
#define NSQ 512
#define NMAT (NB*NSQ)   // 8192
#define NF 1024         // 32*32
#define NSWEEP 7        // 6 sweeps FAILS (absmax 0.195); 7 hits the comparison floor.
#define SB 36           // LDS row stride (floats): 144B = multiple of 16 -> b128-aligned rows

// ---------------------------------------------------------------------------
// Kernel A: Cayley maps. C = (I - X)(I + X)^{-1}, X = W - W^T.
// ---------------------------------------------------------------------------
__global__ __launch_bounds__(64) void cayley_kernel(
    const float* __restrict__ qw, const float* __restrict__ kw,
    const float* __restrict__ vw, float* __restrict__ Cout) {
  __shared__ float M[32][33];
  __shared__ float R[32][33];
  __shared__ float fac[32];
  const float* W = (blockIdx.x == 0) ? qw : ((blockIdx.x == 1) ? kw : vw);
  const int t = threadIdx.x;
  for (int idx = t; idx < 1024; idx += 64) {
    int i = idx >> 5, j = idx & 31;
    float xv = W[i*32+j] - W[j*32+i];
    float d = (i == j) ? 1.0f : 0.0f;
    M[i][j] = d - xv;
    R[i][j] = d + xv;
  }
  __syncthreads();
  for (int k = 0; k < 32; ++k) {
    float inv = 1.0f / M[k][k];
    __syncthreads();
    if (t < 32) M[k][t] *= inv; else R[k][t-32] *= inv;
    __syncthreads();
    if (t < 32) fac[t] = M[t][k];
    __syncthreads();
    if (t < 32) {
      float mk = M[k][t];
      for (int i = 0; i < 32; ++i) {
        if (i == k) continue;
        M[i][t] -= fac[i] * mk;
      }
    } else {
      int tc = t - 32;
      float rk = R[k][tc];
      for (int i = 0; i < 32; ++i) {
        if (i == k) continue;
        R[i][tc] -= fac[i] * rk;
      }
    }
    __syncthreads();
  }
  // R = C^T ; store C row-major: C[p][q] = R[q][p]
  for (int idx = t; idx < 1024; idx += 64) {
    int p = idx >> 5, q = idx & 31;
    Cout[blockIdx.x * 1024 + idx] = R[q][p];
  }
}

// ---------------------------------------------------------------------------
// Kernel B: per-matrix sym eigendecomposition (parallel Jacobi, XOR pairing),
// then q/k/v = offdiag(C S_offdiag C^T) + q2/k2 norms, via the 2-buffer
// identity  C S_offdiag C^T = (C V) L (C V)^T - C diag(S) C^T :
//   Dt[k][i] = <Vt row k, C row i>;  s_l = sum_k Vt[k][l]^2 lw[k];
//   Z[i][j]  = sum_k Dt[k][i] lw[k] Dt[k][j] - sum_l C[i][l] s_l C[j][l].
// Only TWO 32xSB buffers -> LDS ~9.7 KB -> up to 16 workgroups/CU (was 11).
// One 64-thread (single wave) block per matrix.
// A-update: two-phase b128 at r==1 (verified R7); scalar pi-swap 2x2 blocks
// for r>=2. [History: fused-chunk r<=3 (R4/R5) and two-phase r<=3 (R6) FAILED
// (absmax 0.18/0.056) — r==2/3 variants have an unidentified defect; do not
// resurrect without an empirical bisect.]
// ---------------------------------------------------------------------------
__global__ __launch_bounds__(64, 4) void logm_qkv_kernel(
    const float* __restrict__ x, const float* __restrict__ Cm,
    float* __restrict__ qo, float* __restrict__ ko, float* __restrict__ vo,
    float* __restrict__ q2, float* __restrict__ k2) {
  __shared__ __align__(16) float buf0[32*SB];   // A -> (per w) C -> Dt
  __shared__ __align__(16) float buf1[32*SB];   // Vt (stable through epilogue)
  __shared__ __align__(16) float2 cs[16];
  __shared__ __align__(16) float lw[32];
  __shared__ __align__(16) float sd[32];
  const int t = threadIdx.x;
  const int m = blockIdx.x;
  const float* xm = x + (size_t)m * NF;

  // init A = x (stride SB, b128) and Vt = I
  #pragma unroll
  for (int s = 0; s < 4; ++s) {
    int fi = t + 64*s;               // float4 index 0..255
    int i = fi >> 3, j4 = (fi & 7) << 2;
    float4 xv = *(const float4*)&xm[(size_t)fi*4];
    *(float4*)&buf0[i*SB + j4] = xv;
    float4 iv;
    iv.x = (i == j4+0) ? 1.0f : 0.0f;
    iv.y = (i == j4+1) ? 1.0f : 0.0f;
    iv.z = (i == j4+2) ? 1.0f : 0.0f;
    iv.w = (i == j4+3) ? 1.0f : 0.0f;
    *(float4*)&buf1[i*SB + j4] = iv;
  }
  __syncthreads();

  const int ab = t >> 4;       // row-pair group 0..3
  const int bI = t & 15;       // col-pair index
  const int pi = ab & 1;       // role-swap parity

  for (int sw = 0; sw < NSWEEP; ++sw) {
    for (int r = 1; r < 32; ++r) {
      const int h = 31 - __builtin_clz((unsigned)r);
      const int lowmask = (1 << h) - 1;
      // phase 1: rotation angles for the 16 disjoint pairs {p, p^r}
      if (t < 16) {
        int p = ((t >> h) << (h+1)) | (t & lowmask);
        int q = p ^ r;
        float apq = buf0[p*SB+q];
        float c = 1.0f, s = 0.0f;
        if (fabsf(apq) > 1e-36f) {
          float app = buf0[p*SB+p];
          float aqq = buf0[q*SB+q];
          float tau = (aqq - app) / (2.0f * apq);
          float tt = 1.0f / (fabsf(tau) + sqrtf(1.0f + tau*tau));
          tt = (tau < 0.0f) ? -tt : tt;
          c = 1.0f / sqrtf(1.0f + tt*tt);
          s = tt * c;
        }
        cs[t] = make_float2(c, s);
      }
      __syncthreads();
      if (r == 1) {
        // --- phase A: row rotations B = J^T A (b128); pairs (2k,2k+1) ---
        #pragma unroll
        for (int vtk = 0; vtk < 2; ++vtk) {
          int tsk = t + 64*vtk;
          int pr = tsk >> 3;               // pair 0..15
          int ch = (tsk & 7) << 2;         // column chunk
          int p = pr << 1;                 // h=0 -> p = 2*pr
          int q = p | 1;
          float2 c2 = cs[pr];
          float4 ap = *(float4*)&buf0[p*SB + ch];
          float4 aq = *(float4*)&buf0[q*SB + ch];
          float4 np, nq;
          np.x = c2.x*ap.x - c2.y*aq.x;  nq.x = fmaf(c2.y, ap.x, c2.x*aq.x);
          np.y = c2.x*ap.y - c2.y*aq.y;  nq.y = fmaf(c2.y, ap.y, c2.x*aq.y);
          np.z = c2.x*ap.z - c2.y*aq.z;  nq.z = fmaf(c2.y, ap.z, c2.x*aq.z);
          np.w = c2.x*ap.w - c2.y*aq.w;  nq.w = fmaf(c2.y, ap.w, c2.x*aq.w);
          *(float4*)&buf0[p*SB + ch] = np;
          *(float4*)&buf0[q*SB + ch] = nq;
        }
        __syncthreads();   // r is loop-uniform -> all threads reach this
        // --- phase B: col rotations A' = B J, in-register per row-chunk;
        //     local col pairs (0,1) w/ cs[2c] and (2,3) w/ cs[2c+1] ---
        #pragma unroll
        for (int s4 = 0; s4 < 4; ++s4) {
          int tsk = t + 64*s4;             // 0..255
          int i = tsk >> 3;                // row 0..31
          int cch = tsk & 7;               // chunk 0..7 (cols 4c..4c+3)
          float2 cA = cs[2*cch];
          float2 cB = cs[2*cch+1];
          float4 y = *(float4*)&buf0[i*SB + 4*cch];
          float4 z;
          z.x = cA.x*y.x - cA.y*y.y;  z.y = fmaf(cA.y, y.x, cA.x*y.y);
          z.z = cB.x*y.z - cB.y*y.w;  z.w = fmaf(cB.y, y.z, cB.x*y.w);
          *(float4*)&buf0[i*SB + 4*cch] = z;
        }
      } else {
        // blocked 2x2 scalar update, pi-swapped for bank spread (known-good).
        int pb = ((bI >> h) << (h+1)) | (bI & lowmask);
        int qb = pb ^ r;
        if (pi) { int tmp = pb; pb = qb; qb = tmp; }
        const float2 cb2 = cs[bI];
        const float cbb = cb2.x;
        const float sbb = pi ? -cb2.y : cb2.y;
        #pragma unroll
        for (int u = 0; u < 4; ++u) {
          int a = ab + 4*u;
          int pa = ((a >> h) << (h+1)) | (a & lowmask);
          int qa = pa ^ r;
          if (pi) { int tmp = pa; pa = qa; qa = tmp; }
          float2 ca2 = cs[a];
          float caa = ca2.x;
          float saa = pi ? -ca2.y : ca2.y;
          float* rp = buf0 + pa*SB;
          float* rq = buf0 + qa*SB;
          float x11 = rp[pb], x12 = rp[qb];
          float x21 = rq[pb], x22 = rq[qb];
          float y11 = caa*x11 - saa*x21;
          float y12 = caa*x12 - saa*x22;
          float y21 = fmaf(saa, x11, caa*x21);
          float y22 = fmaf(saa, x12, caa*x22);
          rp[pb] = cbb*y11 - sbb*y12;
          rp[qb] = fmaf(sbb, y11, cbb*y12);
          rq[pb] = cbb*y21 - sbb*y22;
          rq[qb] = fmaf(sbb, y21, cbb*y22);
        }
      }
      // V^T row rotations (V = V J  <=>  Vt = J^T Vt), float4 chunks
      #pragma unroll
      for (int vtk = 0; vtk < 2; ++vtk) {
        int tsk = t + 64*vtk;
        int pr = tsk >> 3;               // pair 0..15
        int ch = (tsk & 7) << 2;         // column chunk
        int p = ((pr >> h) << (h+1)) | (pr & lowmask);
        int q = p ^ r;
        float2 c2 = cs[pr];
        float4 vp = *(float4*)&buf1[p*SB + ch];
        float4 vq = *(float4*)&buf1[q*SB + ch];
        float4 np, nq;
        np.x = c2.x*vp.x - c2.y*vq.x;  nq.x = fmaf(c2.y, vp.x, c2.x*vq.x);
        np.y = c2.x*vp.y - c2.y*vq.y;  nq.y = fmaf(c2.y, vp.y, c2.x*vq.y);
        np.z = c2.x*vp.z - c2.y*vq.z;  nq.z = fmaf(c2.y, vp.z, c2.x*vq.z);
        np.w = c2.x*vp.w - c2.y*vq.w;  nq.w = fmaf(c2.y, vp.w, c2.x*vq.w);
        *(float4*)&buf1[p*SB + ch] = np;
        *(float4*)&buf1[q*SB + ch] = nq;
      }
      __syncthreads();
    }
  }

  // eigenvalue logs from A's diagonal
  if (t < 32) lw[t] = logf(fmaxf(buf0[t*SB+t], 1e-30f));
  __syncthreads();
  // s_l = sum_k Vt[k][l]^2 * lw[k]   (diag of S = V L V^T)
  if (t < 32) {
    float s = 0.0f;
    for (int k = 0; k < 32; ++k) {
      float vv = buf1[k*SB + t];
      s = fmaf(vv*vv, lw[k], s);
    }
    sd[t] = s;
  }
  __syncthreads();

  const int rg = t >> 3, cg = t & 7;
  const int i0 = rg*4, j0 = cg*4;   // output tile; also Dt row/col tile
  for (int w = 0; w < 3; ++w) {
    const float* Cw = Cm + w*1024;
    // load C -> buf0 (over dead A / previous Dt), b128 both sides
    #pragma unroll
    for (int s = 0; s < 4; ++s) {
      int fi = t + 64*s;
      int i = fi >> 3, c4 = (fi & 7) << 2;
      *(float4*)&buf0[i*SB + c4] = *(const float4*)&Cw[fi*4];
    }
    __syncthreads();
    // fused: Dt[i0+d][j0+e] = sum_l Vt[i0+d][l] C[j0+e][l]   (dacc)
    //        corr[d][e]     = sum_l C[i0+d][l] sd[l] C[j0+e][l]
    float dacc[4][4] = {};
    float corr[4][4] = {};
    #pragma unroll
    for (int l4 = 0; l4 < 32; l4 += 4) {
      float4 sv = *(float4*)&sd[l4];
      float4 av[4], bv[4], cv[4];
      #pragma unroll
      for (int d = 0; d < 4; ++d) {
        av[d] = *(float4*)&buf1[(i0+d)*SB + l4];   // Vt rows
        bv[d] = *(float4*)&buf0[(j0+d)*SB + l4];   // C rows (shared operand)
        float4 c4v = *(float4*)&buf0[(i0+d)*SB + l4];  // C rows (corr)
        cv[d].x = c4v.x*sv.x; cv[d].y = c4v.y*sv.y; cv[d].z = c4v.z*sv.z; cv[d].w = c4v.w*sv.w;
      }
      #pragma unroll
      for (int d = 0; d < 4; ++d)
        #pragma unroll
        for (int e = 0; e < 4; ++e) {
          dacc[d][e] = fmaf(av[d].x, bv[e].x, dacc[d][e]);
          dacc[d][e] = fmaf(av[d].y, bv[e].y, dacc[d][e]);
          dacc[d][e] = fmaf(av[d].z, bv[e].z, dacc[d][e]);
          dacc[d][e] = fmaf(av[d].w, bv[e].w, dacc[d][e]);
          corr[d][e] = fmaf(cv[d].x, bv[e].x, corr[d][e]);
          corr[d][e] = fmaf(cv[d].y, bv[e].y, corr[d][e]);
          corr[d][e] = fmaf(cv[d].z, bv[e].z, corr[d][e]);
          corr[d][e] = fmaf(cv[d].w, bv[e].w, corr[d][e]);
        }
    }
    __syncthreads();   // all C reads done before Dt overwrites buf0
    #pragma unroll
    for (int d = 0; d < 4; ++d) {
      float4 z; z.x = dacc[d][0]; z.y = dacc[d][1]; z.z = dacc[d][2]; z.w = dacc[d][3];
      *(float4*)&buf0[(i0+d)*SB + j0] = z;   // Dt[i0+d][j0..j0+3]
    }
    __syncthreads();
    // Z[i][j] = sum_k Dt[k][i] lw[k] Dt[k][j] - corr; offdiag -> global
    {
      float acc[4][4] = {};
      for (int k = 0; k < 32; ++k) {
        float lwk = lw[k];
        float4 a4 = *(float4*)&buf0[k*SB + i0];
        float4 b4 = *(float4*)&buf0[k*SB + j0];
        float4 as; as.x = a4.x*lwk; as.y = a4.y*lwk; as.z = a4.z*lwk; as.w = a4.w*lwk;
        acc[0][0]=fmaf(as.x,b4.x,acc[0][0]); acc[0][1]=fmaf(as.x,b4.y,acc[0][1]);
        acc[0][2]=fmaf(as.x,b4.z,acc[0][2]); acc[0][3]=fmaf(as.x,b4.w,acc[0][3]);
        acc[1][0]=fmaf(as.y,b4.x,acc[1][0]); acc[1][1]=fmaf(as.y,b4.y,acc[1][1]);
        acc[1][2]=fmaf(as.y,b4.z,acc[1][2]); acc[1][3]=fmaf(as.y,b4.w,acc[1][3]);
        acc[2][0]=fmaf(as.z,b4.x,acc[2][0]); acc[2][1]=fmaf(as.z,b4.y,acc[2][1]);
        acc[2][2]=fmaf(as.z,b4.z,acc[2][2]); acc[2][3]=fmaf(as.z,b4.w,acc[2][3]);
        acc[3][0]=fmaf(as.w,b4.x,acc[3][0]); acc[3][1]=fmaf(as.w,b4.y,acc[3][1]);
        acc[3][2]=fmaf(as.w,b4.z,acc[3][2]); acc[3][3]=fmaf(as.w,b4.w,acc[3][3]);
      }
      float ss = 0.0f;
      float* outp = (w == 0) ? qo : ((w == 1) ? ko : vo);
      #pragma unroll
      for (int d = 0; d < 4; ++d) {
        #pragma unroll
        for (int e = 0; e < 4; ++e) acc[d][e] -= corr[d][e];
        if (rg == cg) acc[d][d] = 0.0f;
        ss = fmaf(acc[d][0], acc[d][0], ss);
        ss = fmaf(acc[d][1], acc[d][1], ss);
        ss = fmaf(acc[d][2], acc[d][2], ss);
        ss = fmaf(acc[d][3], acc[d][3], ss);
        float4 z; z.x = acc[d][0]; z.y = acc[d][1]; z.z = acc[d][2]; z.w = acc[d][3];
        *(float4*)&outp[(size_t)m*NF + (i0+d)*32 + j0] = z;
      }
      if (w < 2) {
        #pragma unroll
        for (int off = 32; off > 0; off >>= 1)
          ss += __shfl_down(ss, off);
        if (t == 0) ((w == 0) ? q2 : k2)[m] = ss;
      }
    }
    __syncthreads();   // Z reads of buf0 done before next w's C load
  }
}

// ---------------------------------------------------------------------------
// Kernel C1: G[b,j,i] = <kf[b,j], qf[b,i]> (K=1024), fused scores epilogue.
// ---------------------------------------------------------------------------
__global__ __launch_bounds__(256) void scores_kernel(
    const float* __restrict__ qf, const float* __restrict__ kf,
    const float* __restrict__ q2, const float* __restrict__ k2,
    float* __restrict__ P) {
  __shared__ float Ks[64][17];
  __shared__ float Qs[64][17];
  const int b = blockIdx.z;
  const int j0 = blockIdx.y * 64;
  const int i0 = blockIdx.x * 64;
  const int tx = threadIdx.x & 15, ty = threadIdx.x >> 4;
  const int lrow = threadIdx.x >> 2;
  const int lc4 = (threadIdx.x & 3) * 4;
  float acc[4][4] = {};
  const float* kb = kf + (size_t)(b*NSQ + j0) * NF;
  const float* qb = qf + (size_t)(b*NSQ + i0) * NF;
  for (int f0 = 0; f0 < NF; f0 += 16) {
    float4 kv = *(const float4*)(kb + (size_t)lrow*NF + f0 + lc4);
    float4 qv = *(const float4*)(qb + (size_t)lrow*NF + f0 + lc4);
    Ks[lrow][lc4+0] = kv.x; Ks[lrow][lc4+1] = kv.y; Ks[lrow][lc4+2] = kv.z; Ks[lrow][lc4+3] = kv.w;
    Qs[lrow][lc4+0] = qv.x; Qs[lrow][lc4+1] = qv.y; Qs[lrow][lc4+2] = qv.z; Qs[lrow][lc4+3] = qv.w;
    __syncthreads();
    #pragma unroll
    for (int kk = 0; kk < 16; ++kk) {
      float a0 = Ks[ty*4+0][kk], a1 = Ks[ty*4+1][kk], a2 = Ks[ty*4+2][kk], a3 = Ks[ty*4+3][kk];
      float b0 = Qs[tx*4+0][kk], b1 = Qs[tx*4+1][kk], b2 = Qs[tx*4+2][kk], b3 = Qs[tx*4+3][kk];
      acc[0][0]=fmaf(a0,b0,acc[0][0]); acc[0][1]=fmaf(a0,b1,acc[0][1]);
      acc[0][2]=fmaf(a0,b2,acc[0][2]); acc[0][3]=fmaf(a0,b3,acc[0][3]);
      acc[1][0]=fmaf(a1,b0,acc[1][0]); acc[1][1]=fmaf(a1,b1,acc[1][1]);
      acc[1][2]=fmaf(a1,b2,acc[1][2]); acc[1][3]=fmaf(a1,b3,acc[1][3]);
      acc[2][0]=fmaf(a2,b0,acc[2][0]); acc[2][1]=fmaf(a2,b1,acc[2][1]);
      acc[2][2]=fmaf(a2,b2,acc[2][2]); acc[2][3]=fmaf(a2,b3,acc[2][3]);
      acc[3][0]=fmaf(a3,b0,acc[3][0]); acc[3][1]=fmaf(a3,b1,acc[3][1]);
      acc[3][2]=fmaf(a3,b2,acc[3][2]); acc[3][3]=fmaf(a3,b3,acc[3][3]);
    }
    __syncthreads();
  }
  #pragma unroll
  for (int u = 0; u < 4; ++u) {
    int j = j0 + ty*4 + u;
    float kj = k2[b*NSQ + j];
    #pragma unroll
    for (int vv = 0; vv < 4; ++vv) {
      int i = i0 + tx*4 + vv;
      float d2 = kj + q2[b*NSQ + i] - 2.0f * acc[u][vv];
      float e = sqrtf(fmaxf(d2, 1e-12f));
      float sc = 1.0f / (1.0f + log1pf(e));
      P[(size_t)(b*NSQ + j)*NSQ + i] = sc;
    }
  }
}

// ---------------------------------------------------------------------------
// Kernel C1b: softmax over j (axis -2) for each (b,i) column, in place.
// ---------------------------------------------------------------------------
__global__ __launch_bounds__(256) void softmax_kernel(float* __restrict__ P) {
  __shared__ float red[4][64];
  const int b = blockIdx.x >> 3;
  const int i0 = (blockIdx.x & 7) * 64;
  const int il = threadIdx.x & 63;
  const int jg = threadIdx.x >> 6;   // 0..3
  float* base = P + (size_t)b*NSQ*NSQ + i0 + il;
  float mx = -1e30f;
  for (int j = jg*128; j < jg*128 + 128; ++j)
    mx = fmaxf(mx, base[(size_t)j*NSQ]);
  red[jg][il] = mx;
  __syncthreads();
  float cm = fmaxf(fmaxf(red[0][il], red[1][il]), fmaxf(red[2][il], red[3][il]));
  float ssum = 0.0f;
  for (int j = jg*128; j < jg*128 + 128; ++j)
    ssum += expf(base[(size_t)j*NSQ] - cm);
  __syncthreads();
  red[jg][il] = ssum;
  __syncthreads();
  float inv = 1.0f / (red[0][il] + red[1][il] + red[2][il] + red[3][il]);
  for (int j = jg*128; j < jg*128 + 128; ++j) {
    size_t o = (size_t)j*NSQ;
    base[o] = expf(base[o] - cm) * inv;
  }
}

// ---------------------------------------------------------------------------
// Kernel C2: out[b,c,f] = sum_a P[b,c,a] * vf[b,a,f]   (NN GEMM, K=512)
// ---------------------------------------------------------------------------
__global__ __launch_bounds__(256) void out_gemm_kernel(
    const float* __restrict__ P, const float* __restrict__ vf,
    float* __restrict__ out) {
  __shared__ float Ps[64][17];
  __shared__ float Vs[16][68];
  const int b = blockIdx.z;
  const int c0 = blockIdx.y * 64;
  const int f0 = blockIdx.x * 64;
  const int tx = threadIdx.x & 15, ty = threadIdx.x >> 4;
  float acc[4][4] = {};
  const float* Pb = P + (size_t)b * NSQ * NSQ;
  const float* Vb = vf + (size_t)b * NSQ * NF;
  for (int a0 = 0; a0 < NSQ; a0 += 16) {
    {
      int row = threadIdx.x >> 2;
      int c4 = (threadIdx.x & 3) * 4;
      float4 pv = *(const float4*)(Pb + (size_t)(c0 + row) * NSQ + a0 + c4);
      Ps[row][c4+0]=pv.x; Ps[row][c4+1]=pv.y; Ps[row][c4+2]=pv.z; Ps[row][c4+3]=pv.w;
    }
    {
      int row = threadIdx.x >> 4;
      int c4 = (threadIdx.x & 15) * 4;
      float4 vv4 = *(const float4*)(Vb + (size_t)(a0 + row) * NF + f0 + c4);
      Vs[row][c4+0]=vv4.x; Vs[row][c4+1]=vv4.y; Vs[row][c4+2]=vv4.z; Vs[row][c4+3]=vv4.w;
    }
    __syncthreads();
    #pragma unroll
    for (int kk = 0; kk < 16; ++kk) {
      float a0r = Ps[ty*4+0][kk], a1r = Ps[ty*4+1][kk], a2r = Ps[ty*4+2][kk], a3r = Ps[ty*4+3][kk];
      float b0 = Vs[kk][tx*4+0], b1 = Vs[kk][tx*4+1], b2 = Vs[kk][tx*4+2], b3 = Vs[kk][tx*4+3];
      acc[0][0]=fmaf(a0r,b0,acc[0][0]); acc[0][1]=fmaf(a0r,b1,acc[0][1]);
      acc[0][2]=fmaf(a0r,b2,acc[0][2]); acc[0][3]=fmaf(a0r,b3,acc[0][3]);
      acc[1][0]=fmaf(a1r,b0,acc[1][0]); acc[1][1]=fmaf(a1r,b1,acc[1][1]);
      acc[1][2]=fmaf(a1r,b2,acc[1][2]); acc[1][3]=fmaf(a1r,b3,acc[1][3]);
      acc[2][0]=fmaf(a2r,b0,acc[2][0]); acc[2][1]=fmaf(a2r,b1,acc[2][1]);
      acc[2][2]=fmaf(a2r,b2,acc[2][2]); acc[2][3]=fmaf(a2r,b3,acc[2][3]);
      acc[3][0]=fmaf(a3r,b0,acc[3][0]); acc[3][1]=fmaf(a3r,b1,acc[3][1]);
      acc[3][2]=fmaf(a3r,b2,acc[3][2]); acc[3][3]=fmaf(a3r,b3,acc[3][3]);
    }
    __syncthreads();
  }
  #pragma unroll
  for (int u = 0; u < 4; ++u) {
    float4 o;
    o.x = acc[u][0]; o.y = acc[u][1]; o.z = acc[u][2]; o.w = acc[u][3];
    *(float4*)(out + (size_t)(b*NSQ + c0 + ty*4 + u) * NF + f0 + tx*4) = o;
  }
}

extern "C" void kernel_launch(void* const* d_in, const int* in_sizes, int n_in,
                              void* d_out, int out_size, void* d_ws, size_t ws_size,
                              hipStream_t stream) {
  const float* x  = (const float*)d_in[0];
  const float* qw = (const float*)d_in[1];
  const float* kw = (const float*)d_in[2];
  const float* vw = (const float*)d_in[3];
  float* ws = (float*)d_ws;
  float* C  = ws;
  float* q  = ws + 3072;
  float* k  = q + (size_t)NMAT * NF;
  float* v  = k + (size_t)NMAT * NF;
  float* q2 = v + (size_t)NMAT * NF;
  float* k2 = q2 + NMAT;
  float* P  = k2 + NMAT;
  float* out = (float*)d_out;

  cayley_kernel<<<dim3(3), dim3(64), 0, stream>>>(qw, kw, vw, C);
  logm_qkv_kernel<<<dim3(NMAT), dim3(64), 0, stream>>>(x, C, q, k, v, q2, k2);
  scores_kernel<<<dim3(8, 8, NB), dim3(256), 0, stream>>>(q, k, q2, k2, P);
  softmax_kernel<<<dim3(NB * 8), dim3(256), 0, stream>>>(P);
  out_gemm_kernel<<<dim3(16, 8, NB), dim3(256), 0, stream>>>(P, v, out);
}

// Round 9
// 2318.955 us; speedup vs baseline: 1.0854x; 1.0854x over previous
//
#include <hip/hip_runtime.h>
#include <math.h>

#define NB 16
#define NSQ 512
#define NMAT (NB*NSQ)   // 8192
#define NF 1024         // 32*32
#define NSWEEP 7        // 6 sweeps FAILS (absmax 0.195); 7 hits the comparison floor.
#define SB 36           // LDS row stride (floats): 144B = multiple of 16 -> b128-aligned rows

// ---------------------------------------------------------------------------
// Kernel A: Cayley maps. C = (I - X)(I + X)^{-1}, X = W - W^T.
// ---------------------------------------------------------------------------
__global__ __launch_bounds__(64) void cayley_kernel(
    const float* __restrict__ qw, const float* __restrict__ kw,
    const float* __restrict__ vw, float* __restrict__ Cout) {
  __shared__ float M[32][33];
  __shared__ float R[32][33];
  __shared__ float fac[32];
  const float* W = (blockIdx.x == 0) ? qw : ((blockIdx.x == 1) ? kw : vw);
  const int t = threadIdx.x;
  for (int idx = t; idx < 1024; idx += 64) {
    int i = idx >> 5, j = idx & 31;
    float xv = W[i*32+j] - W[j*32+i];
    float d = (i == j) ? 1.0f : 0.0f;
    M[i][j] = d - xv;
    R[i][j] = d + xv;
  }
  __syncthreads();
  for (int k = 0; k < 32; ++k) {
    float inv = 1.0f / M[k][k];
    __syncthreads();
    if (t < 32) M[k][t] *= inv; else R[k][t-32] *= inv;
    __syncthreads();
    if (t < 32) fac[t] = M[t][k];
    __syncthreads();
    if (t < 32) {
      float mk = M[k][t];
      for (int i = 0; i < 32; ++i) {
        if (i == k) continue;
        M[i][t] -= fac[i] * mk;
      }
    } else {
      int tc = t - 32;
      float rk = R[k][tc];
      for (int i = 0; i < 32; ++i) {
        if (i == k) continue;
        R[i][tc] -= fac[i] * rk;
      }
    }
    __syncthreads();
  }
  // R = C^T ; store C row-major: C[p][q] = R[q][p]
  for (int idx = t; idx < 1024; idx += 64) {
    int p = idx >> 5, q = idx & 31;
    Cout[blockIdx.x * 1024 + idx] = R[q][p];
  }
}

// ---------------------------------------------------------------------------
// Kernel B: per-matrix sym eigendecomposition (parallel Jacobi, XOR pairing),
// then q/k/v = offdiag(C S_offdiag C^T) + q2/k2 norms, via the 2-buffer
// identity  C S_offdiag C^T = (C V) L (C V)^T - C diag(S) C^T :
//   Dt[k][i] = <Vt row k, C row i>;  s_l = sum_k Vt[k][l]^2 lw[k];
//   Z[i][j]  = sum_k Dt[k][i] lw[k] Dt[k][j] - sum_l C[i][l] s_l C[j][l].
// Only TWO 32xSB buffers -> LDS ~9.7 KB -> up to 16 workgroups/CU.
// [R8 LESSON: __launch_bounds__(64,4) capped VGPRs at 64 -> epilogue spilled
//  to scratch -> 5.85 GB HBM traffic, kernel 2x SLOWER. Plain bounds + split
//  epilogue loops keep peak live set ~85 regs, no spill.]
// A-update: two-phase b128 at r==1 (verified R7); scalar pi-swap 2x2 blocks
// for r>=2. [History: fused-chunk r<=3 (R4/R5) and two-phase r<=3 (R6) FAILED
// (absmax 0.18/0.056) — r==2/3 variants have an unidentified defect.]
// ---------------------------------------------------------------------------
__global__ __launch_bounds__(64) void logm_qkv_kernel(
    const float* __restrict__ x, const float* __restrict__ Cm,
    float* __restrict__ qo, float* __restrict__ ko, float* __restrict__ vo,
    float* __restrict__ q2, float* __restrict__ k2) {
  __shared__ __align__(16) float buf0[32*SB];   // A -> (per w) C -> Dt
  __shared__ __align__(16) float buf1[32*SB];   // Vt (stable through epilogue)
  __shared__ __align__(16) float2 cs[16];
  __shared__ __align__(16) float lw[32];
  __shared__ __align__(16) float sd[32];
  const int t = threadIdx.x;
  const int m = blockIdx.x;
  const float* xm = x + (size_t)m * NF;

  // init A = x (stride SB, b128) and Vt = I
  #pragma unroll
  for (int s = 0; s < 4; ++s) {
    int fi = t + 64*s;               // float4 index 0..255
    int i = fi >> 3, j4 = (fi & 7) << 2;
    float4 xv = *(const float4*)&xm[(size_t)fi*4];
    *(float4*)&buf0[i*SB + j4] = xv;
    float4 iv;
    iv.x = (i == j4+0) ? 1.0f : 0.0f;
    iv.y = (i == j4+1) ? 1.0f : 0.0f;
    iv.z = (i == j4+2) ? 1.0f : 0.0f;
    iv.w = (i == j4+3) ? 1.0f : 0.0f;
    *(float4*)&buf1[i*SB + j4] = iv;
  }
  __syncthreads();

  const int ab = t >> 4;       // row-pair group 0..3
  const int bI = t & 15;       // col-pair index
  const int pi = ab & 1;       // role-swap parity

  for (int sw = 0; sw < NSWEEP; ++sw) {
    for (int r = 1; r < 32; ++r) {
      const int h = 31 - __builtin_clz((unsigned)r);
      const int lowmask = (1 << h) - 1;
      // phase 1: rotation angles for the 16 disjoint pairs {p, p^r}
      if (t < 16) {
        int p = ((t >> h) << (h+1)) | (t & lowmask);
        int q = p ^ r;
        float apq = buf0[p*SB+q];
        float c = 1.0f, s = 0.0f;
        if (fabsf(apq) > 1e-36f) {
          float app = buf0[p*SB+p];
          float aqq = buf0[q*SB+q];
          float tau = (aqq - app) / (2.0f * apq);
          float tt = 1.0f / (fabsf(tau) + sqrtf(1.0f + tau*tau));
          tt = (tau < 0.0f) ? -tt : tt;
          c = 1.0f / sqrtf(1.0f + tt*tt);
          s = tt * c;
        }
        cs[t] = make_float2(c, s);
      }
      __syncthreads();
      if (r == 1) {
        // --- phase A: row rotations B = J^T A (b128); pairs (2k,2k+1) ---
        #pragma unroll
        for (int vtk = 0; vtk < 2; ++vtk) {
          int tsk = t + 64*vtk;
          int pr = tsk >> 3;               // pair 0..15
          int ch = (tsk & 7) << 2;         // column chunk
          int p = pr << 1;                 // h=0 -> p = 2*pr
          int q = p | 1;
          float2 c2 = cs[pr];
          float4 ap = *(float4*)&buf0[p*SB + ch];
          float4 aq = *(float4*)&buf0[q*SB + ch];
          float4 np, nq;
          np.x = c2.x*ap.x - c2.y*aq.x;  nq.x = fmaf(c2.y, ap.x, c2.x*aq.x);
          np.y = c2.x*ap.y - c2.y*aq.y;  nq.y = fmaf(c2.y, ap.y, c2.x*aq.y);
          np.z = c2.x*ap.z - c2.y*aq.z;  nq.z = fmaf(c2.y, ap.z, c2.x*aq.z);
          np.w = c2.x*ap.w - c2.y*aq.w;  nq.w = fmaf(c2.y, ap.w, c2.x*aq.w);
          *(float4*)&buf0[p*SB + ch] = np;
          *(float4*)&buf0[q*SB + ch] = nq;
        }
        __syncthreads();   // r is loop-uniform -> all threads reach this
        // --- phase B: col rotations A' = B J, in-register per row-chunk;
        //     local col pairs (0,1) w/ cs[2c] and (2,3) w/ cs[2c+1] ---
        #pragma unroll
        for (int s4 = 0; s4 < 4; ++s4) {
          int tsk = t + 64*s4;             // 0..255
          int i = tsk >> 3;                // row 0..31
          int cch = tsk & 7;               // chunk 0..7 (cols 4c..4c+3)
          float2 cA = cs[2*cch];
          float2 cB = cs[2*cch+1];
          float4 y = *(float4*)&buf0[i*SB + 4*cch];
          float4 z;
          z.x = cA.x*y.x - cA.y*y.y;  z.y = fmaf(cA.y, y.x, cA.x*y.y);
          z.z = cB.x*y.z - cB.y*y.w;  z.w = fmaf(cB.y, y.z, cB.x*y.w);
          *(float4*)&buf0[i*SB + 4*cch] = z;
        }
      } else {
        // blocked 2x2 scalar update, pi-swapped for bank spread (known-good).
        int pb = ((bI >> h) << (h+1)) | (bI & lowmask);
        int qb = pb ^ r;
        if (pi) { int tmp = pb; pb = qb; qb = tmp; }
        const float2 cb2 = cs[bI];
        const float cbb = cb2.x;
        const float sbb = pi ? -cb2.y : cb2.y;
        #pragma unroll
        for (int u = 0; u < 4; ++u) {
          int a = ab + 4*u;
          int pa = ((a >> h) << (h+1)) | (a & lowmask);
          int qa = pa ^ r;
          if (pi) { int tmp = pa; pa = qa; qa = tmp; }
          float2 ca2 = cs[a];
          float caa = ca2.x;
          float saa = pi ? -ca2.y : ca2.y;
          float* rp = buf0 + pa*SB;
          float* rq = buf0 + qa*SB;
          float x11 = rp[pb], x12 = rp[qb];
          float x21 = rq[pb], x22 = rq[qb];
          float y11 = caa*x11 - saa*x21;
          float y12 = caa*x12 - saa*x22;
          float y21 = fmaf(saa, x11, caa*x21);
          float y22 = fmaf(saa, x12, caa*x22);
          rp[pb] = cbb*y11 - sbb*y12;
          rp[qb] = fmaf(sbb, y11, cbb*y12);
          rq[pb] = cbb*y21 - sbb*y22;
          rq[qb] = fmaf(sbb, y21, cbb*y22);
        }
      }
      // V^T row rotations (V = V J  <=>  Vt = J^T Vt), float4 chunks
      #pragma unroll
      for (int vtk = 0; vtk < 2; ++vtk) {
        int tsk = t + 64*vtk;
        int pr = tsk >> 3;               // pair 0..15
        int ch = (tsk & 7) << 2;         // column chunk
        int p = ((pr >> h) << (h+1)) | (pr & lowmask);
        int q = p ^ r;
        float2 c2 = cs[pr];
        float4 vp = *(float4*)&buf1[p*SB + ch];
        float4 vq = *(float4*)&buf1[q*SB + ch];
        float4 np, nq;
        np.x = c2.x*vp.x - c2.y*vq.x;  nq.x = fmaf(c2.y, vp.x, c2.x*vq.x);
        np.y = c2.x*vp.y - c2.y*vq.y;  nq.y = fmaf(c2.y, vp.y, c2.x*vq.y);
        np.z = c2.x*vp.z - c2.y*vq.z;  nq.z = fmaf(c2.y, vp.z, c2.x*vq.z);
        np.w = c2.x*vp.w - c2.y*vq.w;  nq.w = fmaf(c2.y, vp.w, c2.x*vq.w);
        *(float4*)&buf1[p*SB + ch] = np;
        *(float4*)&buf1[q*SB + ch] = nq;
      }
      __syncthreads();
    }
  }

  // eigenvalue logs from A's diagonal
  if (t < 32) lw[t] = logf(fmaxf(buf0[t*SB+t], 1e-30f));
  __syncthreads();
  // s_l = sum_k Vt[k][l]^2 * lw[k]   (diag of S = V L V^T)
  if (t < 32) {
    float s = 0.0f;
    for (int k = 0; k < 32; ++k) {
      float vv = buf1[k*SB + t];
      s = fmaf(vv*vv, lw[k], s);
    }
    sd[t] = s;
  }
  __syncthreads();

  const int rg = t >> 3, cg = t & 7;
  const int i0 = rg*4, j0 = cg*4;   // output tile; also Dt row/col tile
  for (int w = 0; w < 3; ++w) {
    const float* Cw = Cm + w*1024;
    // load C -> buf0 (over dead A / previous Dt), b128 both sides
    #pragma unroll
    for (int s = 0; s < 4; ++s) {
      int fi = t + 64*s;
      int i = fi >> 3, c4 = (fi & 7) << 2;
      *(float4*)&buf0[i*SB + c4] = *(const float4*)&Cw[fi*4];
    }
    __syncthreads();
    // pass 1: corr[d][e] = sum_l C[i0+d][l] sd[l] C[j0+e][l]
    float corr[4][4] = {};
    #pragma unroll
    for (int l4 = 0; l4 < 32; l4 += 4) {
      float4 sv = *(float4*)&sd[l4];
      float4 cv[4], bv[4];
      #pragma unroll
      for (int d = 0; d < 4; ++d) {
        float4 c4v = *(float4*)&buf0[(i0+d)*SB + l4];
        cv[d].x = c4v.x*sv.x; cv[d].y = c4v.y*sv.y; cv[d].z = c4v.z*sv.z; cv[d].w = c4v.w*sv.w;
        bv[d] = *(float4*)&buf0[(j0+d)*SB + l4];
      }
      #pragma unroll
      for (int d = 0; d < 4; ++d)
        #pragma unroll
        for (int e = 0; e < 4; ++e) {
          corr[d][e] = fmaf(cv[d].x, bv[e].x, corr[d][e]);
          corr[d][e] = fmaf(cv[d].y, bv[e].y, corr[d][e]);
          corr[d][e] = fmaf(cv[d].z, bv[e].z, corr[d][e]);
          corr[d][e] = fmaf(cv[d].w, bv[e].w, corr[d][e]);
        }
    }
    // pass 2: dacc[d][e] = Dt[i0+d][j0+e] = sum_l Vt[i0+d][l] C[j0+e][l]
    float dacc[4][4] = {};
    #pragma unroll
    for (int l4 = 0; l4 < 32; l4 += 4) {
      float4 av[4], bv[4];
      #pragma unroll
      for (int d = 0; d < 4; ++d) {
        av[d] = *(float4*)&buf1[(i0+d)*SB + l4];   // Vt rows
        bv[d] = *(float4*)&buf0[(j0+d)*SB + l4];   // C rows
      }
      #pragma unroll
      for (int d = 0; d < 4; ++d)
        #pragma unroll
        for (int e = 0; e < 4; ++e) {
          dacc[d][e] = fmaf(av[d].x, bv[e].x, dacc[d][e]);
          dacc[d][e] = fmaf(av[d].y, bv[e].y, dacc[d][e]);
          dacc[d][e] = fmaf(av[d].z, bv[e].z, dacc[d][e]);
          dacc[d][e] = fmaf(av[d].w, bv[e].w, dacc[d][e]);
        }
    }
    __syncthreads();   // all C reads done before Dt overwrites buf0
    #pragma unroll
    for (int d = 0; d < 4; ++d) {
      float4 z; z.x = dacc[d][0]; z.y = dacc[d][1]; z.z = dacc[d][2]; z.w = dacc[d][3];
      *(float4*)&buf0[(i0+d)*SB + j0] = z;   // Dt[i0+d][j0..j0+3]
    }
    __syncthreads();
    // Z[i][j] = sum_k Dt[k][i] lw[k] Dt[k][j] - corr; offdiag -> global
    {
      float acc[4][4] = {};
      for (int k = 0; k < 32; ++k) {
        float lwk = lw[k];
        float4 a4 = *(float4*)&buf0[k*SB + i0];
        float4 b4 = *(float4*)&buf0[k*SB + j0];
        float4 as; as.x = a4.x*lwk; as.y = a4.y*lwk; as.z = a4.z*lwk; as.w = a4.w*lwk;
        acc[0][0]=fmaf(as.x,b4.x,acc[0][0]); acc[0][1]=fmaf(as.x,b4.y,acc[0][1]);
        acc[0][2]=fmaf(as.x,b4.z,acc[0][2]); acc[0][3]=fmaf(as.x,b4.w,acc[0][3]);
        acc[1][0]=fmaf(as.y,b4.x,acc[1][0]); acc[1][1]=fmaf(as.y,b4.y,acc[1][1]);
        acc[1][2]=fmaf(as.y,b4.z,acc[1][2]); acc[1][3]=fmaf(as.y,b4.w,acc[1][3]);
        acc[2][0]=fmaf(as.z,b4.x,acc[2][0]); acc[2][1]=fmaf(as.z,b4.y,acc[2][1]);
        acc[2][2]=fmaf(as.z,b4.z,acc[2][2]); acc[2][3]=fmaf(as.z,b4.w,acc[2][3]);
        acc[3][0]=fmaf(as.w,b4.x,acc[3][0]); acc[3][1]=fmaf(as.w,b4.y,acc[3][1]);
        acc[3][2]=fmaf(as.w,b4.z,acc[3][2]); acc[3][3]=fmaf(as.w,b4.w,acc[3][3]);
      }
      float ss = 0.0f;
      float* outp = (w == 0) ? qo : ((w == 1) ? ko : vo);
      #pragma unroll
      for (int d = 0; d < 4; ++d) {
        #pragma unroll
        for (int e = 0; e < 4; ++e) acc[d][e] -= corr[d][e];
        if (rg == cg) acc[d][d] = 0.0f;
        ss = fmaf(acc[d][0], acc[d][0], ss);
        ss = fmaf(acc[d][1], acc[d][1], ss);
        ss = fmaf(acc[d][2], acc[d][2], ss);
        ss = fmaf(acc[d][3], acc[d][3], ss);
        float4 z; z.x = acc[d][0]; z.y = acc[d][1]; z.z = acc[d][2]; z.w = acc[d][3];
        *(float4*)&outp[(size_t)m*NF + (i0+d)*32 + j0] = z;
      }
      if (w < 2) {
        #pragma unroll
        for (int off = 32; off > 0; off >>= 1)
          ss += __shfl_down(ss, off);
        if (t == 0) ((w == 0) ? q2 : k2)[m] = ss;
      }
    }
    __syncthreads();   // Z reads of buf0 done before next w's C load
  }
}

// ---------------------------------------------------------------------------
// Kernel C1: G[b,j,i] = <kf[b,j], qf[b,i]> (K=1024), fused scores epilogue.
// ---------------------------------------------------------------------------
__global__ __launch_bounds__(256) void scores_kernel(
    const float* __restrict__ qf, const float* __restrict__ kf,
    const float* __restrict__ q2, const float* __restrict__ k2,
    float* __restrict__ P) {
  __shared__ float Ks[64][17];
  __shared__ float Qs[64][17];
  const int b = blockIdx.z;
  const int j0 = blockIdx.y * 64;
  const int i0 = blockIdx.x * 64;
  const int tx = threadIdx.x & 15, ty = threadIdx.x >> 4;
  const int lrow = threadIdx.x >> 2;
  const int lc4 = (threadIdx.x & 3) * 4;
  float acc[4][4] = {};
  const float* kb = kf + (size_t)(b*NSQ + j0) * NF;
  const float* qb = qf + (size_t)(b*NSQ + i0) * NF;
  for (int f0 = 0; f0 < NF; f0 += 16) {
    float4 kv = *(const float4*)(kb + (size_t)lrow*NF + f0 + lc4);
    float4 qv = *(const float4*)(qb + (size_t)lrow*NF + f0 + lc4);
    Ks[lrow][lc4+0] = kv.x; Ks[lrow][lc4+1] = kv.y; Ks[lrow][lc4+2] = kv.z; Ks[lrow][lc4+3] = kv.w;
    Qs[lrow][lc4+0] = qv.x; Qs[lrow][lc4+1] = qv.y; Qs[lrow][lc4+2] = qv.z; Qs[lrow][lc4+3] = qv.w;
    __syncthreads();
    #pragma unroll
    for (int kk = 0; kk < 16; ++kk) {
      float a0 = Ks[ty*4+0][kk], a1 = Ks[ty*4+1][kk], a2 = Ks[ty*4+2][kk], a3 = Ks[ty*4+3][kk];
      float b0 = Qs[tx*4+0][kk], b1 = Qs[tx*4+1][kk], b2 = Qs[tx*4+2][kk], b3 = Qs[tx*4+3][kk];
      acc[0][0]=fmaf(a0,b0,acc[0][0]); acc[0][1]=fmaf(a0,b1,acc[0][1]);
      acc[0][2]=fmaf(a0,b2,acc[0][2]); acc[0][3]=fmaf(a0,b3,acc[0][3]);
      acc[1][0]=fmaf(a1,b0,acc[1][0]); acc[1][1]=fmaf(a1,b1,acc[1][1]);
      acc[1][2]=fmaf(a1,b2,acc[1][2]); acc[1][3]=fmaf(a1,b3,acc[1][3]);
      acc[2][0]=fmaf(a2,b0,acc[2][0]); acc[2][1]=fmaf(a2,b1,acc[2][1]);
      acc[2][2]=fmaf(a2,b2,acc[2][2]); acc[2][3]=fmaf(a2,b3,acc[2][3]);
      acc[3][0]=fmaf(a3,b0,acc[3][0]); acc[3][1]=fmaf(a3,b1,acc[3][1]);
      acc[3][2]=fmaf(a3,b2,acc[3][2]); acc[3][3]=fmaf(a3,b3,acc[3][3]);
    }
    __syncthreads();
  }
  #pragma unroll
  for (int u = 0; u < 4; ++u) {
    int j = j0 + ty*4 + u;
    float kj = k2[b*NSQ + j];
    #pragma unroll
    for (int vv = 0; vv < 4; ++vv) {
      int i = i0 + tx*4 + vv;
      float d2 = kj + q2[b*NSQ + i] - 2.0f * acc[u][vv];
      float e = sqrtf(fmaxf(d2, 1e-12f));
      float sc = 1.0f / (1.0f + log1pf(e));
      P[(size_t)(b*NSQ + j)*NSQ + i] = sc;
    }
  }
}

// ---------------------------------------------------------------------------
// Kernel C1b: softmax over j (axis -2) for each (b,i) column, in place.
// ---------------------------------------------------------------------------
__global__ __launch_bounds__(256) void softmax_kernel(float* __restrict__ P) {
  __shared__ float red[4][64];
  const int b = blockIdx.x >> 3;
  const int i0 = (blockIdx.x & 7) * 64;
  const int il = threadIdx.x & 63;
  const int jg = threadIdx.x >> 6;   // 0..3
  float* base = P + (size_t)b*NSQ*NSQ + i0 + il;
  float mx = -1e30f;
  for (int j = jg*128; j < jg*128 + 128; ++j)
    mx = fmaxf(mx, base[(size_t)j*NSQ]);
  red[jg][il] = mx;
  __syncthreads();
  float cm = fmaxf(fmaxf(red[0][il], red[1][il]), fmaxf(red[2][il], red[3][il]));
  float ssum = 0.0f;
  for (int j = jg*128; j < jg*128 + 128; ++j)
    ssum += expf(base[(size_t)j*NSQ] - cm);
  __syncthreads();
  red[jg][il] = ssum;
  __syncthreads();
  float inv = 1.0f / (red[0][il] + red[1][il] + red[2][il] + red[3][il]);
  for (int j = jg*128; j < jg*128 + 128; ++j) {
    size_t o = (size_t)j*NSQ;
    base[o] = expf(base[o] - cm) * inv;
  }
}

// ---------------------------------------------------------------------------
// Kernel C2: out[b,c,f] = sum_a P[b,c,a] * vf[b,a,f]   (NN GEMM, K=512)
// ---------------------------------------------------------------------------
__global__ __launch_bounds__(256) void out_gemm_kernel(
    const float* __restrict__ P, const float* __restrict__ vf,
    float* __restrict__ out) {
  __shared__ float Ps[64][17];
  __shared__ float Vs[16][68];
  const int b = blockIdx.z;
  const int c0 = blockIdx.y * 64;
  const int f0 = blockIdx.x * 64;
  const int tx = threadIdx.x & 15, ty = threadIdx.x >> 4;
  float acc[4][4] = {};
  const float* Pb = P + (size_t)b * NSQ * NSQ;
  const float* Vb = vf + (size_t)b * NSQ * NF;
  for (int a0 = 0; a0 < NSQ; a0 += 16) {
    {
      int row = threadIdx.x >> 2;
      int c4 = (threadIdx.x & 3) * 4;
      float4 pv = *(const float4*)(Pb + (size_t)(c0 + row) * NSQ + a0 + c4);
      Ps[row][c4+0]=pv.x; Ps[row][c4+1]=pv.y; Ps[row][c4+2]=pv.z; Ps[row][c4+3]=pv.w;
    }
    {
      int row = threadIdx.x >> 4;
      int c4 = (threadIdx.x & 15) * 4;
      float4 vv4 = *(const float4*)(Vb + (size_t)(a0 + row) * NF + f0 + c4);
      Vs[row][c4+0]=vv4.x; Vs[row][c4+1]=vv4.y; Vs[row][c4+2]=vv4.z; Vs[row][c4+3]=vv4.w;
    }
    __syncthreads();
    #pragma unroll
    for (int kk = 0; kk < 16; ++kk) {
      float a0r = Ps[ty*4+0][kk], a1r = Ps[ty*4+1][kk], a2r = Ps[ty*4+2][kk], a3r = Ps[ty*4+3][kk];
      float b0 = Vs[kk][tx*4+0], b1 = Vs[kk][tx*4+1], b2 = Vs[kk][tx*4+2], b3 = Vs[kk][tx*4+3];
      acc[0][0]=fmaf(a0r,b0,acc[0][0]); acc[0][1]=fmaf(a0r,b1,acc[0][1]);
      acc[0][2]=fmaf(a0r,b2,acc[0][2]); acc[0][3]=fmaf(a0r,b3,acc[0][3]);
      acc[1][0]=fmaf(a1r,b0,acc[1][0]); acc[1][1]=fmaf(a1r,b1,acc[1][1]);
      acc[1][2]=fmaf(a1r,b2,acc[1][2]); acc[1][3]=fmaf(a1r,b3,acc[1][3]);
      acc[2][0]=fmaf(a2r,b0,acc[2][0]); acc[2][1]=fmaf(a2r,b1,acc[2][1]);
      acc[2][2]=fmaf(a2r,b2,acc[2][2]); acc[2][3]=fmaf(a2r,b3,acc[2][3]);
      acc[3][0]=fmaf(a3r,b0,acc[3][0]); acc[3][1]=fmaf(a3r,b1,acc[3][1]);
      acc[3][2]=fmaf(a3r,b2,acc[3][2]); acc[3][3]=fmaf(a3r,b3,acc[3][3]);
    }
    __syncthreads();
  }
  #pragma unroll
  for (int u = 0; u < 4; ++u) {
    float4 o;
    o.x = acc[u][0]; o.y = acc[u][1]; o.z = acc[u][2]; o.w = acc[u][3];
    *(float4*)(out + (size_t)(b*NSQ + c0 + ty*4 + u) * NF + f0 + tx*4) = o;
  }
}

extern "C" void kernel_launch(void* const* d_in, const int* in_sizes, int n_in,
                              void* d_out, int out_size, void* d_ws, size_t ws_size,
                              hipStream_t stream) {
  const float* x  = (const float*)d_in[0];
  const float* qw = (const float*)d_in[1];
  const float* kw = (const float*)d_in[2];
  const float* vw = (const float*)d_in[3];
  float* ws = (float*)d_ws;
  float* C  = ws;
  float* q  = ws + 3072;
  float* k  = q + (size_t)NMAT * NF;
  float* v  = k + (size_t)NMAT * NF;
  float* q2 = v + (size_t)NMAT * NF;
  float* k2 = q2 + NMAT;
  float* P  = k2 + NMAT;
  float* out = (float*)d_out;

  cayley_kernel<<<dim3(3), dim3(64), 0, stream>>>(qw, kw, vw, C);
  logm_qkv_kernel<<<dim3(NMAT), dim3(64), 0, stream>>>(x, C, q, k, v, q2, k2);
  scores_kernel<<<dim3(8, 8, NB), dim3(256), 0, stream>>>(q, k, q2, k2, P);
  softmax_kernel<<<dim3(NB * 8), dim3(256), 0, stream>>>(P);
  out_gemm_kernel<<<dim3(16, 8, NB), dim3(256), 0, stream>>>(P, v, out);
}

// Round 10
// 1451.540 us; speedup vs baseline: 1.7341x; 1.5976x over previous
//
#include <hip/hip_runtime.h>
#include <math.h>

#define NB 16
#define NSQ 512
#define NMAT (NB*NSQ)   // 8192
#define NF 1024         // 32*32
#define NSWEEP 7        // 6 sweeps FAILS (absmax 0.195); 7 hits the comparison floor.
#define SB 36           // LDS row stride (floats): 144B = multiple of 16 -> b128-aligned rows

// ---------------------------------------------------------------------------
// Kernel A: Cayley maps. C = (I - X)(I + X)^{-1}, X = W - W^T.
// ---------------------------------------------------------------------------
__global__ __launch_bounds__(64) void cayley_kernel(
    const float* __restrict__ qw, const float* __restrict__ kw,
    const float* __restrict__ vw, float* __restrict__ Cout) {
  __shared__ float M[32][33];
  __shared__ float R[32][33];
  __shared__ float fac[32];
  const float* W = (blockIdx.x == 0) ? qw : ((blockIdx.x == 1) ? kw : vw);
  const int t = threadIdx.x;
  for (int idx = t; idx < 1024; idx += 64) {
    int i = idx >> 5, j = idx & 31;
    float xv = W[i*32+j] - W[j*32+i];
    float d = (i == j) ? 1.0f : 0.0f;
    M[i][j] = d - xv;
    R[i][j] = d + xv;
  }
  __syncthreads();
  for (int k = 0; k < 32; ++k) {
    float inv = 1.0f / M[k][k];
    __syncthreads();
    if (t < 32) M[k][t] *= inv; else R[k][t-32] *= inv;
    __syncthreads();
    if (t < 32) fac[t] = M[t][k];
    __syncthreads();
    if (t < 32) {
      float mk = M[k][t];
      for (int i = 0; i < 32; ++i) {
        if (i == k) continue;
        M[i][t] -= fac[i] * mk;
      }
    } else {
      int tc = t - 32;
      float rk = R[k][tc];
      for (int i = 0; i < 32; ++i) {
        if (i == k) continue;
        R[i][tc] -= fac[i] * rk;
      }
    }
    __syncthreads();
  }
  // R = C^T ; store C row-major: C[p][q] = R[q][p]
  for (int idx = t; idx < 1024; idx += 64) {
    int p = idx >> 5, q = idx & 31;
    Cout[blockIdx.x * 1024 + idx] = R[q][p];
  }
}

// ---------------------------------------------------------------------------
// Kernel B: per-matrix sym eigendecomposition (parallel Jacobi, XOR pairing),
// then S = V log(w) V^T (zero diag), then q/k/v = offdiag(C S C^T) + norms.
// TWO waves (128 threads) per matrix: same arithmetic as the verified R7
// single-wave kernel, work split across 2 waves to double waves/CU (LDS
// 14336 B -> 11 blocks/CU -> 22 waves/CU vs 11) and hide LDS latency.
// [R8/R9 LESSON: 2-buffer LDS epilogues cost registers (spill at bound=64,
//  VGPR=232 unbounded) and LOSE. Keep the 3-buffer R7 epilogue shape.]
// A-update: two-phase b128 at r==1 (verified R7); scalar pi-swap 2x2 blocks
// for r>=2. [R4/R5/R6: fused/two-phase r<=3 variants FAILED — do not revisit.]
// ---------------------------------------------------------------------------
__global__ __launch_bounds__(128) void logm_qkv_kernel(
    const float* __restrict__ x, const float* __restrict__ Cm,
    float* __restrict__ qo, float* __restrict__ ko, float* __restrict__ vo,
    float* __restrict__ q2, float* __restrict__ k2) {
  __shared__ __align__(16) float buf0[32*SB];   // A -> Vrow -> (per w) C
  __shared__ __align__(16) float buf1[32*SB];   // Vt -> T (=offdiag S)
  __shared__ __align__(16) float buf2[32*SB];   // U
  __shared__ __align__(16) float2 cs[16];
  __shared__ __align__(16) float lw[32];
  __shared__ float wsum[2];
  const int t = threadIdx.x;
  const int m = blockIdx.x;
  const float* xm = x + (size_t)m * NF;

  // init A = x (stride SB, b128) and Vt = I : 256 float4 tasks, 2/thread
  #pragma unroll
  for (int s = 0; s < 2; ++s) {
    int fi = t + 128*s;              // float4 index 0..255
    int i = fi >> 3, j4 = (fi & 7) << 2;
    float4 xv = *(const float4*)&xm[(size_t)fi*4];
    *(float4*)&buf0[i*SB + j4] = xv;
    float4 iv;
    iv.x = (i == j4+0) ? 1.0f : 0.0f;
    iv.y = (i == j4+1) ? 1.0f : 0.0f;
    iv.z = (i == j4+2) ? 1.0f : 0.0f;
    iv.w = (i == j4+3) ? 1.0f : 0.0f;
    *(float4*)&buf1[i*SB + j4] = iv;
  }
  __syncthreads();

  const int abase = t >> 4;    // row-pair group 0..7
  const int bI = t & 15;       // col-pair index
  const int pi = abase & 1;    // role-swap parity

  for (int sw = 0; sw < NSWEEP; ++sw) {
    for (int r = 1; r < 32; ++r) {
      const int h = 31 - __builtin_clz((unsigned)r);
      const int lowmask = (1 << h) - 1;
      // phase 1: rotation angles for the 16 disjoint pairs {p, p^r}
      if (t < 16) {
        int p = ((t >> h) << (h+1)) | (t & lowmask);
        int q = p ^ r;
        float apq = buf0[p*SB+q];
        float c = 1.0f, s = 0.0f;
        if (fabsf(apq) > 1e-36f) {
          float app = buf0[p*SB+p];
          float aqq = buf0[q*SB+q];
          float tau = (aqq - app) / (2.0f * apq);
          float tt = 1.0f / (fabsf(tau) + sqrtf(1.0f + tau*tau));
          tt = (tau < 0.0f) ? -tt : tt;
          c = 1.0f / sqrtf(1.0f + tt*tt);
          s = tt * c;
        }
        cs[t] = make_float2(c, s);
      }
      __syncthreads();
      if (r == 1) {
        // --- phase A: row rotations B = J^T A (b128); pairs (2k,2k+1);
        //     128 tasks (16 pairs x 8 chunks), 1 per thread ---
        {
          int pr = t >> 3;                 // pair 0..15
          int ch = (t & 7) << 2;           // column chunk
          int p = pr << 1;                 // h=0 -> p = 2*pr
          int q = p | 1;
          float2 c2 = cs[pr];
          float4 ap = *(float4*)&buf0[p*SB + ch];
          float4 aq = *(float4*)&buf0[q*SB + ch];
          float4 np, nq;
          np.x = c2.x*ap.x - c2.y*aq.x;  nq.x = fmaf(c2.y, ap.x, c2.x*aq.x);
          np.y = c2.x*ap.y - c2.y*aq.y;  nq.y = fmaf(c2.y, ap.y, c2.x*aq.y);
          np.z = c2.x*ap.z - c2.y*aq.z;  nq.z = fmaf(c2.y, ap.z, c2.x*aq.z);
          np.w = c2.x*ap.w - c2.y*aq.w;  nq.w = fmaf(c2.y, ap.w, c2.x*aq.w);
          *(float4*)&buf0[p*SB + ch] = np;
          *(float4*)&buf0[q*SB + ch] = nq;
        }
        __syncthreads();   // r is loop-uniform -> all threads reach this
        // --- phase B: col rotations A' = B J, in-register per row-chunk;
        //     local col pairs (0,1) w/ cs[2c] and (2,3) w/ cs[2c+1];
        //     256 tasks, 2 per thread ---
        #pragma unroll
        for (int s4 = 0; s4 < 2; ++s4) {
          int tsk = t + 128*s4;            // 0..255
          int i = tsk >> 3;                // row 0..31
          int cch = tsk & 7;               // chunk 0..7 (cols 4c..4c+3)
          float2 cA = cs[2*cch];
          float2 cB = cs[2*cch+1];
          float4 y = *(float4*)&buf0[i*SB + 4*cch];
          float4 z;
          z.x = cA.x*y.x - cA.y*y.y;  z.y = fmaf(cA.y, y.x, cA.x*y.y);
          z.z = cB.x*y.z - cB.y*y.w;  z.w = fmaf(cB.y, y.z, cB.x*y.w);
          *(float4*)&buf0[i*SB + 4*cch] = z;
        }
      } else {
        // blocked 2x2 scalar update, pi-swapped; 256 blocks, 2 per thread.
        int pb = ((bI >> h) << (h+1)) | (bI & lowmask);
        int qb = pb ^ r;
        if (pi) { int tmp = pb; pb = qb; qb = tmp; }
        const float2 cb2 = cs[bI];
        const float cbb = cb2.x;
        const float sbb = pi ? -cb2.y : cb2.y;
        #pragma unroll
        for (int u = 0; u < 2; ++u) {
          int a = abase + 8*u;
          int pa = ((a >> h) << (h+1)) | (a & lowmask);
          int qa = pa ^ r;
          if (pi) { int tmp = pa; pa = qa; qa = tmp; }
          float2 ca2 = cs[a];
          float caa = ca2.x;
          float saa = pi ? -ca2.y : ca2.y;
          float* rp = buf0 + pa*SB;
          float* rq = buf0 + qa*SB;
          float x11 = rp[pb], x12 = rp[qb];
          float x21 = rq[pb], x22 = rq[qb];
          float y11 = caa*x11 - saa*x21;
          float y12 = caa*x12 - saa*x22;
          float y21 = fmaf(saa, x11, caa*x21);
          float y22 = fmaf(saa, x12, caa*x22);
          rp[pb] = cbb*y11 - sbb*y12;
          rp[qb] = fmaf(sbb, y11, cbb*y12);
          rq[pb] = cbb*y21 - sbb*y22;
          rq[qb] = fmaf(sbb, y21, cbb*y22);
        }
      }
      // V^T row rotations (Vt = J^T Vt), 128 float4 tasks, 1 per thread
      {
        int pr = t >> 3;                 // pair 0..15
        int ch = (t & 7) << 2;           // column chunk
        int p = ((pr >> h) << (h+1)) | (pr & lowmask);
        int q = p ^ r;
        float2 c2 = cs[pr];
        float4 vp = *(float4*)&buf1[p*SB + ch];
        float4 vq = *(float4*)&buf1[q*SB + ch];
        float4 np, nq;
        np.x = c2.x*vp.x - c2.y*vq.x;  nq.x = fmaf(c2.y, vp.x, c2.x*vq.x);
        np.y = c2.x*vp.y - c2.y*vq.y;  nq.y = fmaf(c2.y, vp.y, c2.x*vq.y);
        np.z = c2.x*vp.z - c2.y*vq.z;  nq.z = fmaf(c2.y, vp.z, c2.x*vq.z);
        np.w = c2.x*vp.w - c2.y*vq.w;  nq.w = fmaf(c2.y, vp.w, c2.x*vq.w);
        *(float4*)&buf1[p*SB + ch] = np;
        *(float4*)&buf1[q*SB + ch] = nq;
      }
      __syncthreads();
    }
  }

  if (t < 32) lw[t] = logf(fmaxf(buf0[t*SB+t], 1e-30f));
  __syncthreads();
  // transpose Vt(buf1) -> Vrow(buf0): 1024 scalars, 8 per thread
  #pragma unroll
  for (int s = 0; s < 8; ++s) {
    int idx = t + 128*s;
    int i = idx >> 5, k = idx & 31;
    buf0[i*SB + k] = buf1[k*SB + i];
  }
  __syncthreads();

  // tile partition: 128 threads own 4x2 output tiles (8 row-groups x 16 col-groups)
  const int rg = t >> 4, cg = t & 15;
  const int i0 = rg*4, j0 = cg*2;
  // T = offdiag(S), S[i][j] = sum_k (Vrow[i][k]*lw[k]) * Vrow[j][k]  -> buf1
  {
    float acc[4][2] = {};
    #pragma unroll
    for (int k4 = 0; k4 < 32; k4 += 4) {
      float4 lv = *(float4*)&lw[k4];
      float4 av[4], bv[2];
      #pragma unroll
      for (int d = 0; d < 4; ++d) {
        float4 a4 = *(float4*)&buf0[(i0+d)*SB + k4];
        av[d].x = a4.x*lv.x; av[d].y = a4.y*lv.y; av[d].z = a4.z*lv.z; av[d].w = a4.w*lv.w;
      }
      #pragma unroll
      for (int e = 0; e < 2; ++e)
        bv[e] = *(float4*)&buf0[(j0+e)*SB + k4];
      #pragma unroll
      for (int d = 0; d < 4; ++d)
        #pragma unroll
        for (int e = 0; e < 2; ++e) {
          acc[d][e] = fmaf(av[d].x, bv[e].x, acc[d][e]);
          acc[d][e] = fmaf(av[d].y, bv[e].y, acc[d][e]);
          acc[d][e] = fmaf(av[d].z, bv[e].z, acc[d][e]);
          acc[d][e] = fmaf(av[d].w, bv[e].w, acc[d][e]);
        }
    }
    #pragma unroll
    for (int d = 0; d < 4; ++d) {
      #pragma unroll
      for (int e = 0; e < 2; ++e)
        if (i0+d == j0+e) acc[d][e] = 0.0f;
      float2 z; z.x = acc[d][0]; z.y = acc[d][1];
      *(float2*)&buf1[(i0+d)*SB + j0] = z;
    }
  }
  __syncthreads();

  for (int w = 0; w < 3; ++w) {
    const float* Cw = Cm + w*1024;
    // load C -> buf0 (over dead Vrow), 256 float4, 2 per thread
    #pragma unroll
    for (int s = 0; s < 2; ++s) {
      int fi = t + 128*s;
      int i = fi >> 3, c4 = (fi & 7) << 2;
      *(float4*)&buf0[i*SB + c4] = *(const float4*)&Cw[fi*4];
    }
    __syncthreads();
    // U = C * T (T symmetric): U[i][j] = sum_k C[i][k] * T[j][k] -> buf2
    {
      float acc[4][2] = {};
      #pragma unroll
      for (int k4 = 0; k4 < 32; k4 += 4) {
        float4 av[4], bv[2];
        #pragma unroll
        for (int d = 0; d < 4; ++d)
          av[d] = *(float4*)&buf0[(i0+d)*SB + k4];
        #pragma unroll
        for (int e = 0; e < 2; ++e)
          bv[e] = *(float4*)&buf1[(j0+e)*SB + k4];
        #pragma unroll
        for (int d = 0; d < 4; ++d)
          #pragma unroll
          for (int e = 0; e < 2; ++e) {
            acc[d][e] = fmaf(av[d].x, bv[e].x, acc[d][e]);
            acc[d][e] = fmaf(av[d].y, bv[e].y, acc[d][e]);
            acc[d][e] = fmaf(av[d].z, bv[e].z, acc[d][e]);
            acc[d][e] = fmaf(av[d].w, bv[e].w, acc[d][e]);
          }
      }
      #pragma unroll
      for (int d = 0; d < 4; ++d) {
        float2 z; z.x = acc[d][0]; z.y = acc[d][1];
        *(float2*)&buf2[(i0+d)*SB + j0] = z;
      }
    }
    __syncthreads();
    // Z = U * C^T: Z[i][j] = sum_k U[i][k] * C[j][k]; offdiag -> global
    {
      float acc[4][2] = {};
      #pragma unroll
      for (int k4 = 0; k4 < 32; k4 += 4) {
        float4 av[4], bv[2];
        #pragma unroll
        for (int d = 0; d < 4; ++d)
          av[d] = *(float4*)&buf2[(i0+d)*SB + k4];
        #pragma unroll
        for (int e = 0; e < 2; ++e)
          bv[e] = *(float4*)&buf0[(j0+e)*SB + k4];
        #pragma unroll
        for (int d = 0; d < 4; ++d)
          #pragma unroll
          for (int e = 0; e < 2; ++e) {
            acc[d][e] = fmaf(av[d].x, bv[e].x, acc[d][e]);
            acc[d][e] = fmaf(av[d].y, bv[e].y, acc[d][e]);
            acc[d][e] = fmaf(av[d].z, bv[e].z, acc[d][e]);
            acc[d][e] = fmaf(av[d].w, bv[e].w, acc[d][e]);
          }
      }
      float ss = 0.0f;
      float* outp = (w == 0) ? qo : ((w == 1) ? ko : vo);
      #pragma unroll
      for (int d = 0; d < 4; ++d) {
        #pragma unroll
        for (int e = 0; e < 2; ++e) {
          if (i0+d == j0+e) acc[d][e] = 0.0f;
          ss = fmaf(acc[d][e], acc[d][e], ss);
        }
        float2 z; z.x = acc[d][0]; z.y = acc[d][1];
        *(float2*)&outp[(size_t)m*NF + (i0+d)*32 + j0] = z;
      }
      if (w < 2) {
        #pragma unroll
        for (int off = 32; off > 0; off >>= 1)
          ss += __shfl_down(ss, off);
        if ((t & 63) == 0) wsum[t >> 6] = ss;
      }
      __syncthreads();   // wsum visible; Z reads of buf0/buf2 done
      if (w < 2 && t == 0)
        ((w == 0) ? q2 : k2)[m] = wsum[0] + wsum[1];
    }
  }
}

// ---------------------------------------------------------------------------
// Kernel C1: G[b,j,i] = <kf[b,j], qf[b,i]> (K=1024), fused scores epilogue.
// ---------------------------------------------------------------------------
__global__ __launch_bounds__(256) void scores_kernel(
    const float* __restrict__ qf, const float* __restrict__ kf,
    const float* __restrict__ q2, const float* __restrict__ k2,
    float* __restrict__ P) {
  __shared__ float Ks[64][17];
  __shared__ float Qs[64][17];
  const int b = blockIdx.z;
  const int j0 = blockIdx.y * 64;
  const int i0 = blockIdx.x * 64;
  const int tx = threadIdx.x & 15, ty = threadIdx.x >> 4;
  const int lrow = threadIdx.x >> 2;
  const int lc4 = (threadIdx.x & 3) * 4;
  float acc[4][4] = {};
  const float* kb = kf + (size_t)(b*NSQ + j0) * NF;
  const float* qb = qf + (size_t)(b*NSQ + i0) * NF;
  for (int f0 = 0; f0 < NF; f0 += 16) {
    float4 kv = *(const float4*)(kb + (size_t)lrow*NF + f0 + lc4);
    float4 qv = *(const float4*)(qb + (size_t)lrow*NF + f0 + lc4);
    Ks[lrow][lc4+0] = kv.x; Ks[lrow][lc4+1] = kv.y; Ks[lrow][lc4+2] = kv.z; Ks[lrow][lc4+3] = kv.w;
    Qs[lrow][lc4+0] = qv.x; Qs[lrow][lc4+1] = qv.y; Qs[lrow][lc4+2] = qv.z; Qs[lrow][lc4+3] = qv.w;
    __syncthreads();
    #pragma unroll
    for (int kk = 0; kk < 16; ++kk) {
      float a0 = Ks[ty*4+0][kk], a1 = Ks[ty*4+1][kk], a2 = Ks[ty*4+2][kk], a3 = Ks[ty*4+3][kk];
      float b0 = Qs[tx*4+0][kk], b1 = Qs[tx*4+1][kk], b2 = Qs[tx*4+2][kk], b3 = Qs[tx*4+3][kk];
      acc[0][0]=fmaf(a0,b0,acc[0][0]); acc[0][1]=fmaf(a0,b1,acc[0][1]);
      acc[0][2]=fmaf(a0,b2,acc[0][2]); acc[0][3]=fmaf(a0,b3,acc[0][3]);
      acc[1][0]=fmaf(a1,b0,acc[1][0]); acc[1][1]=fmaf(a1,b1,acc[1][1]);
      acc[1][2]=fmaf(a1,b2,acc[1][2]); acc[1][3]=fmaf(a1,b3,acc[1][3]);
      acc[2][0]=fmaf(a2,b0,acc[2][0]); acc[2][1]=fmaf(a2,b1,acc[2][1]);
      acc[2][2]=fmaf(a2,b2,acc[2][2]); acc[2][3]=fmaf(a2,b3,acc[2][3]);
      acc[3][0]=fmaf(a3,b0,acc[3][0]); acc[3][1]=fmaf(a3,b1,acc[3][1]);
      acc[3][2]=fmaf(a3,b2,acc[3][2]); acc[3][3]=fmaf(a3,b3,acc[3][3]);
    }
    __syncthreads();
  }
  #pragma unroll
  for (int u = 0; u < 4; ++u) {
    int j = j0 + ty*4 + u;
    float kj = k2[b*NSQ + j];
    #pragma unroll
    for (int vv = 0; vv < 4; ++vv) {
      int i = i0 + tx*4 + vv;
      float d2 = kj + q2[b*NSQ + i] - 2.0f * acc[u][vv];
      float e = sqrtf(fmaxf(d2, 1e-12f));
      float sc = 1.0f / (1.0f + log1pf(e));
      P[(size_t)(b*NSQ + j)*NSQ + i] = sc;
    }
  }
}

// ---------------------------------------------------------------------------
// Kernel C1b: softmax over j (axis -2) for each (b,i) column, in place.
// ---------------------------------------------------------------------------
__global__ __launch_bounds__(256) void softmax_kernel(float* __restrict__ P) {
  __shared__ float red[4][64];
  const int b = blockIdx.x >> 3;
  const int i0 = (blockIdx.x & 7) * 64;
  const int il = threadIdx.x & 63;
  const int jg = threadIdx.x >> 6;   // 0..3
  float* base = P + (size_t)b*NSQ*NSQ + i0 + il;
  float mx = -1e30f;
  for (int j = jg*128; j < jg*128 + 128; ++j)
    mx = fmaxf(mx, base[(size_t)j*NSQ]);
  red[jg][il] = mx;
  __syncthreads();
  float cm = fmaxf(fmaxf(red[0][il], red[1][il]), fmaxf(red[2][il], red[3][il]));
  float ssum = 0.0f;
  for (int j = jg*128; j < jg*128 + 128; ++j)
    ssum += expf(base[(size_t)j*NSQ] - cm);
  __syncthreads();
  red[jg][il] = ssum;
  __syncthreads();
  float inv = 1.0f / (red[0][il] + red[1][il] + red[2][il] + red[3][il]);
  for (int j = jg*128; j < jg*128 + 128; ++j) {
    size_t o = (size_t)j*NSQ;
    base[o] = expf(base[o] - cm) * inv;
  }
}

// ---------------------------------------------------------------------------
// Kernel C2: out[b,c,f] = sum_a P[b,c,a] * vf[b,a,f]   (NN GEMM, K=512)
// ---------------------------------------------------------------------------
__global__ __launch_bounds__(256) void out_gemm_kernel(
    const float* __restrict__ P, const float* __restrict__ vf,
    float* __restrict__ out) {
  __shared__ float Ps[64][17];
  __shared__ float Vs[16][68];
  const int b = blockIdx.z;
  const int c0 = blockIdx.y * 64;
  const int f0 = blockIdx.x * 64;
  const int tx = threadIdx.x & 15, ty = threadIdx.x >> 4;
  float acc[4][4] = {};
  const float* Pb = P + (size_t)b * NSQ * NSQ;
  const float* Vb = vf + (size_t)b * NSQ * NF;
  for (int a0 = 0; a0 < NSQ; a0 += 16) {
    {
      int row = threadIdx.x >> 2;
      int c4 = (threadIdx.x & 3) * 4;
      float4 pv = *(const float4*)(Pb + (size_t)(c0 + row) * NSQ + a0 + c4);
      Ps[row][c4+0]=pv.x; Ps[row][c4+1]=pv.y; Ps[row][c4+2]=pv.z; Ps[row][c4+3]=pv.w;
    }
    {
      int row = threadIdx.x >> 4;
      int c4 = (threadIdx.x & 15) * 4;
      float4 vv4 = *(const float4*)(Vb + (size_t)(a0 + row) * NF + f0 + c4);
      Vs[row][c4+0]=vv4.x; Vs[row][c4+1]=vv4.y; Vs[row][c4+2]=vv4.z; Vs[row][c4+3]=vv4.w;
    }
    __syncthreads();
    #pragma unroll
    for (int kk = 0; kk < 16; ++kk) {
      float a0r = Ps[ty*4+0][kk], a1r = Ps[ty*4+1][kk], a2r = Ps[ty*4+2][kk], a3r = Ps[ty*4+3][kk];
      float b0 = Vs[kk][tx*4+0], b1 = Vs[kk][tx*4+1], b2 = Vs[kk][tx*4+2], b3 = Vs[kk][tx*4+3];
      acc[0][0]=fmaf(a0r,b0,acc[0][0]); acc[0][1]=fmaf(a0r,b1,acc[0][1]);
      acc[0][2]=fmaf(a0r,b2,acc[0][2]); acc[0][3]=fmaf(a0r,b3,acc[0][3]);
      acc[1][0]=fmaf(a1r,b0,acc[1][0]); acc[1][1]=fmaf(a1r,b1,acc[1][1]);
      acc[1][2]=fmaf(a1r,b2,acc[1][2]); acc[1][3]=fmaf(a1r,b3,acc[1][3]);
      acc[2][0]=fmaf(a2r,b0,acc[2][0]); acc[2][1]=fmaf(a2r,b1,acc[2][1]);
      acc[2][2]=fmaf(a2r,b2,acc[2][2]); acc[2][3]=fmaf(a2r,b3,acc[2][3]);
      acc[3][0]=fmaf(a3r,b0,acc[3][0]); acc[3][1]=fmaf(a3r,b1,acc[3][1]);
      acc[3][2]=fmaf(a3r,b2,acc[3][2]); acc[3][3]=fmaf(a3r,b3,acc[3][3]);
    }
    __syncthreads();
  }
  #pragma unroll
  for (int u = 0; u < 4; ++u) {
    float4 o;
    o.x = acc[u][0]; o.y = acc[u][1]; o.z = acc[u][2]; o.w = acc[u][3];
    *(float4*)(out + (size_t)(b*NSQ + c0 + ty*4 + u) * NF + f0 + tx*4) = o;
  }
}

extern "C" void kernel_launch(void* const* d_in, const int* in_sizes, int n_in,
                              void* d_out, int out_size, void* d_ws, size_t ws_size,
                              hipStream_t stream) {
  const float* x  = (const float*)d_in[0];
  const float* qw = (const float*)d_in[1];
  const float* kw = (const float*)d_in[2];
  const float* vw = (const float*)d_in[3];
  float* ws = (float*)d_ws;
  float* C  = ws;
  float* q  = ws + 3072;
  float* k  = q + (size_t)NMAT * NF;
  float* v  = k + (size_t)NMAT * NF;
  float* q2 = v + (size_t)NMAT * NF;
  float* k2 = q2 + NMAT;
  float* P  = k2 + NMAT;
  float* out = (float*)d_out;

  cayley_kernel<<<dim3(3), dim3(64), 0, stream>>>(qw, kw, vw, C);
  logm_qkv_kernel<<<dim3(NMAT), dim3(128), 0, stream>>>(x, C, q, k, v, q2, k2);
  scores_kernel<<<dim3(8, 8, NB), dim3(256), 0, stream>>>(q, k, q2, k2, P);
  softmax_kernel<<<dim3(NB * 8), dim3(256), 0, stream>>>(P);
  out_gemm_kernel<<<dim3(16, 8, NB), dim3(256), 0, stream>>>(P, v, out);
}

// Round 11
// 1423.396 us; speedup vs baseline: 1.7684x; 1.0198x over previous
//
#include <hip/hip_runtime.h>
#include <math.h>

#define NB 16
#define NSQ 512
#define NMAT (NB*NSQ)   // 8192
#define NF 1024         // 32*32
#define NSWEEP 7        // 6 sweeps FAILS (absmax 0.195); 7 hits the comparison floor.
#define SB 36           // LDS row stride (floats): 144B = multiple of 16 -> b128-aligned rows

// ---------------------------------------------------------------------------
// Kernel A: Cayley maps. C = (I - X)(I + X)^{-1}, X = W - W^T.
// ---------------------------------------------------------------------------
__global__ __launch_bounds__(64) void cayley_kernel(
    const float* __restrict__ qw, const float* __restrict__ kw,
    const float* __restrict__ vw, float* __restrict__ Cout) {
  __shared__ float M[32][33];
  __shared__ float R[32][33];
  __shared__ float fac[32];
  const float* W = (blockIdx.x == 0) ? qw : ((blockIdx.x == 1) ? kw : vw);
  const int t = threadIdx.x;
  for (int idx = t; idx < 1024; idx += 64) {
    int i = idx >> 5, j = idx & 31;
    float xv = W[i*32+j] - W[j*32+i];
    float d = (i == j) ? 1.0f : 0.0f;
    M[i][j] = d - xv;
    R[i][j] = d + xv;
  }
  __syncthreads();
  for (int k = 0; k < 32; ++k) {
    float inv = 1.0f / M[k][k];
    __syncthreads();
    if (t < 32) M[k][t] *= inv; else R[k][t-32] *= inv;
    __syncthreads();
    if (t < 32) fac[t] = M[t][k];
    __syncthreads();
    if (t < 32) {
      float mk = M[k][t];
      for (int i = 0; i < 32; ++i) {
        if (i == k) continue;
        M[i][t] -= fac[i] * mk;
      }
    } else {
      int tc = t - 32;
      float rk = R[k][tc];
      for (int i = 0; i < 32; ++i) {
        if (i == k) continue;
        R[i][tc] -= fac[i] * rk;
      }
    }
    __syncthreads();
  }
  // R = C^T ; store C row-major: C[p][q] = R[q][p]
  for (int idx = t; idx < 1024; idx += 64) {
    int p = idx >> 5, q = idx & 31;
    Cout[blockIdx.x * 1024 + idx] = R[q][p];
  }
}

// ---------------------------------------------------------------------------
// Kernel B: per-matrix sym eigendecomposition (parallel Jacobi, XOR pairing),
// then S = V log(w) V^T (zero diag), then q/k/v = offdiag(C S C^T) + norms.
// TWO waves (128 threads) per matrix (verified R10: VGPR 52, occ 42%,
// VALUBusy 80% — near the sweep loop's VALU-issue ceiling).
// [R8/R9 LESSON: 2-buffer LDS epilogues cost registers and LOSE.]
// A-update: two-phase b128 at r==1 (verified R7); scalar pi-swap 2x2 blocks
// for r>=2. [R4/R5/R6: fused/two-phase r<=3 variants FAILED — do not revisit.]
// ---------------------------------------------------------------------------
__global__ __launch_bounds__(128) void logm_qkv_kernel(
    const float* __restrict__ x, const float* __restrict__ Cm,
    float* __restrict__ qo, float* __restrict__ ko, float* __restrict__ vo,
    float* __restrict__ q2, float* __restrict__ k2) {
  __shared__ __align__(16) float buf0[32*SB];   // A -> Vrow -> (per w) C
  __shared__ __align__(16) float buf1[32*SB];   // Vt -> T (=offdiag S)
  __shared__ __align__(16) float buf2[32*SB];   // U
  __shared__ __align__(16) float2 cs[16];
  __shared__ __align__(16) float lw[32];
  __shared__ float wsum[2];
  const int t = threadIdx.x;
  const int m = blockIdx.x;
  const float* xm = x + (size_t)m * NF;

  // init A = x (stride SB, b128) and Vt = I : 256 float4 tasks, 2/thread
  #pragma unroll
  for (int s = 0; s < 2; ++s) {
    int fi = t + 128*s;              // float4 index 0..255
    int i = fi >> 3, j4 = (fi & 7) << 2;
    float4 xv = *(const float4*)&xm[(size_t)fi*4];
    *(float4*)&buf0[i*SB + j4] = xv;
    float4 iv;
    iv.x = (i == j4+0) ? 1.0f : 0.0f;
    iv.y = (i == j4+1) ? 1.0f : 0.0f;
    iv.z = (i == j4+2) ? 1.0f : 0.0f;
    iv.w = (i == j4+3) ? 1.0f : 0.0f;
    *(float4*)&buf1[i*SB + j4] = iv;
  }
  __syncthreads();

  const int abase = t >> 4;    // row-pair group 0..7
  const int bI = t & 15;       // col-pair index
  const int pi = abase & 1;    // role-swap parity

  for (int sw = 0; sw < NSWEEP; ++sw) {
    for (int r = 1; r < 32; ++r) {
      const int h = 31 - __builtin_clz((unsigned)r);
      const int lowmask = (1 << h) - 1;
      // phase 1: rotation angles for the 16 disjoint pairs {p, p^r}
      if (t < 16) {
        int p = ((t >> h) << (h+1)) | (t & lowmask);
        int q = p ^ r;
        float apq = buf0[p*SB+q];
        float c = 1.0f, s = 0.0f;
        if (fabsf(apq) > 1e-36f) {
          float app = buf0[p*SB+p];
          float aqq = buf0[q*SB+q];
          float tau = (aqq - app) / (2.0f * apq);
          float tt = 1.0f / (fabsf(tau) + sqrtf(1.0f + tau*tau));
          tt = (tau < 0.0f) ? -tt : tt;
          c = 1.0f / sqrtf(1.0f + tt*tt);
          s = tt * c;
        }
        cs[t] = make_float2(c, s);
      }
      __syncthreads();
      if (r == 1) {
        // --- phase A: row rotations B = J^T A (b128); pairs (2k,2k+1);
        //     128 tasks (16 pairs x 8 chunks), 1 per thread ---
        {
          int pr = t >> 3;                 // pair 0..15
          int ch = (t & 7) << 2;           // column chunk
          int p = pr << 1;                 // h=0 -> p = 2*pr
          int q = p | 1;
          float2 c2 = cs[pr];
          float4 ap = *(float4*)&buf0[p*SB + ch];
          float4 aq = *(float4*)&buf0[q*SB + ch];
          float4 np, nq;
          np.x = c2.x*ap.x - c2.y*aq.x;  nq.x = fmaf(c2.y, ap.x, c2.x*aq.x);
          np.y = c2.x*ap.y - c2.y*aq.y;  nq.y = fmaf(c2.y, ap.y, c2.x*aq.y);
          np.z = c2.x*ap.z - c2.y*aq.z;  nq.z = fmaf(c2.y, ap.z, c2.x*aq.z);
          np.w = c2.x*ap.w - c2.y*aq.w;  nq.w = fmaf(c2.y, ap.w, c2.x*aq.w);
          *(float4*)&buf0[p*SB + ch] = np;
          *(float4*)&buf0[q*SB + ch] = nq;
        }
        __syncthreads();   // r is loop-uniform -> all threads reach this
        // --- phase B: col rotations A' = B J, in-register per row-chunk;
        //     local col pairs (0,1) w/ cs[2c] and (2,3) w/ cs[2c+1];
        //     256 tasks, 2 per thread ---
        #pragma unroll
        for (int s4 = 0; s4 < 2; ++s4) {
          int tsk = t + 128*s4;            // 0..255
          int i = tsk >> 3;                // row 0..31
          int cch = tsk & 7;               // chunk 0..7 (cols 4c..4c+3)
          float2 cA = cs[2*cch];
          float2 cB = cs[2*cch+1];
          float4 y = *(float4*)&buf0[i*SB + 4*cch];
          float4 z;
          z.x = cA.x*y.x - cA.y*y.y;  z.y = fmaf(cA.y, y.x, cA.x*y.y);
          z.z = cB.x*y.z - cB.y*y.w;  z.w = fmaf(cB.y, y.z, cB.x*y.w);
          *(float4*)&buf0[i*SB + 4*cch] = z;
        }
      } else {
        // blocked 2x2 scalar update, pi-swapped; 256 blocks, 2 per thread.
        int pb = ((bI >> h) << (h+1)) | (bI & lowmask);
        int qb = pb ^ r;
        if (pi) { int tmp = pb; pb = qb; qb = tmp; }
        const float2 cb2 = cs[bI];
        const float cbb = cb2.x;
        const float sbb = pi ? -cb2.y : cb2.y;
        #pragma unroll
        for (int u = 0; u < 2; ++u) {
          int a = abase + 8*u;
          int pa = ((a >> h) << (h+1)) | (a & lowmask);
          int qa = pa ^ r;
          if (pi) { int tmp = pa; pa = qa; qa = tmp; }
          float2 ca2 = cs[a];
          float caa = ca2.x;
          float saa = pi ? -ca2.y : ca2.y;
          float* rp = buf0 + pa*SB;
          float* rq = buf0 + qa*SB;
          float x11 = rp[pb], x12 = rp[qb];
          float x21 = rq[pb], x22 = rq[qb];
          float y11 = caa*x11 - saa*x21;
          float y12 = caa*x12 - saa*x22;
          float y21 = fmaf(saa, x11, caa*x21);
          float y22 = fmaf(saa, x12, caa*x22);
          rp[pb] = cbb*y11 - sbb*y12;
          rp[qb] = fmaf(sbb, y11, cbb*y12);
          rq[pb] = cbb*y21 - sbb*y22;
          rq[qb] = fmaf(sbb, y21, cbb*y22);
        }
      }
      // V^T row rotations (Vt = J^T Vt), 128 float4 tasks, 1 per thread
      {
        int pr = t >> 3;                 // pair 0..15
        int ch = (t & 7) << 2;           // column chunk
        int p = ((pr >> h) << (h+1)) | (pr & lowmask);
        int q = p ^ r;
        float2 c2 = cs[pr];
        float4 vp = *(float4*)&buf1[p*SB + ch];
        float4 vq = *(float4*)&buf1[q*SB + ch];
        float4 np, nq;
        np.x = c2.x*vp.x - c2.y*vq.x;  nq.x = fmaf(c2.y, vp.x, c2.x*vq.x);
        np.y = c2.x*vp.y - c2.y*vq.y;  nq.y = fmaf(c2.y, vp.y, c2.x*vq.y);
        np.z = c2.x*vp.z - c2.y*vq.z;  nq.z = fmaf(c2.y, vp.z, c2.x*vq.z);
        np.w = c2.x*vp.w - c2.y*vq.w;  nq.w = fmaf(c2.y, vp.w, c2.x*vq.w);
        *(float4*)&buf1[p*SB + ch] = np;
        *(float4*)&buf1[q*SB + ch] = nq;
      }
      __syncthreads();
    }
  }

  if (t < 32) lw[t] = logf(fmaxf(buf0[t*SB+t], 1e-30f));
  __syncthreads();
  // transpose Vt(buf1) -> Vrow(buf0): 1024 scalars, 8 per thread
  #pragma unroll
  for (int s = 0; s < 8; ++s) {
    int idx = t + 128*s;
    int i = idx >> 5, k = idx & 31;
    buf0[i*SB + k] = buf1[k*SB + i];
  }
  __syncthreads();

  // tile partition: 128 threads own 4x2 output tiles (8 row-groups x 16 col-groups)
  const int rg = t >> 4, cg = t & 15;
  const int i0 = rg*4, j0 = cg*2;
  // T = offdiag(S), S[i][j] = sum_k (Vrow[i][k]*lw[k]) * Vrow[j][k]  -> buf1
  {
    float acc[4][2] = {};
    #pragma unroll
    for (int k4 = 0; k4 < 32; k4 += 4) {
      float4 lv = *(float4*)&lw[k4];
      float4 av[4], bv[2];
      #pragma unroll
      for (int d = 0; d < 4; ++d) {
        float4 a4 = *(float4*)&buf0[(i0+d)*SB + k4];
        av[d].x = a4.x*lv.x; av[d].y = a4.y*lv.y; av[d].z = a4.z*lv.z; av[d].w = a4.w*lv.w;
      }
      #pragma unroll
      for (int e = 0; e < 2; ++e)
        bv[e] = *(float4*)&buf0[(j0+e)*SB + k4];
      #pragma unroll
      for (int d = 0; d < 4; ++d)
        #pragma unroll
        for (int e = 0; e < 2; ++e) {
          acc[d][e] = fmaf(av[d].x, bv[e].x, acc[d][e]);
          acc[d][e] = fmaf(av[d].y, bv[e].y, acc[d][e]);
          acc[d][e] = fmaf(av[d].z, bv[e].z, acc[d][e]);
          acc[d][e] = fmaf(av[d].w, bv[e].w, acc[d][e]);
        }
    }
    #pragma unroll
    for (int d = 0; d < 4; ++d) {
      #pragma unroll
      for (int e = 0; e < 2; ++e)
        if (i0+d == j0+e) acc[d][e] = 0.0f;
      float2 z; z.x = acc[d][0]; z.y = acc[d][1];
      *(float2*)&buf1[(i0+d)*SB + j0] = z;
    }
  }
  __syncthreads();

  for (int w = 0; w < 3; ++w) {
    const float* Cw = Cm + w*1024;
    // load C -> buf0 (over dead Vrow), 256 float4, 2 per thread
    #pragma unroll
    for (int s = 0; s < 2; ++s) {
      int fi = t + 128*s;
      int i = fi >> 3, c4 = (fi & 7) << 2;
      *(float4*)&buf0[i*SB + c4] = *(const float4*)&Cw[fi*4];
    }
    __syncthreads();
    // U = C * T (T symmetric): U[i][j] = sum_k C[i][k] * T[j][k] -> buf2
    {
      float acc[4][2] = {};
      #pragma unroll
      for (int k4 = 0; k4 < 32; k4 += 4) {
        float4 av[4], bv[2];
        #pragma unroll
        for (int d = 0; d < 4; ++d)
          av[d] = *(float4*)&buf0[(i0+d)*SB + k4];
        #pragma unroll
        for (int e = 0; e < 2; ++e)
          bv[e] = *(float4*)&buf1[(j0+e)*SB + k4];
        #pragma unroll
        for (int d = 0; d < 4; ++d)
          #pragma unroll
          for (int e = 0; e < 2; ++e) {
            acc[d][e] = fmaf(av[d].x, bv[e].x, acc[d][e]);
            acc[d][e] = fmaf(av[d].y, bv[e].y, acc[d][e]);
            acc[d][e] = fmaf(av[d].z, bv[e].z, acc[d][e]);
            acc[d][e] = fmaf(av[d].w, bv[e].w, acc[d][e]);
          }
      }
      #pragma unroll
      for (int d = 0; d < 4; ++d) {
        float2 z; z.x = acc[d][0]; z.y = acc[d][1];
        *(float2*)&buf2[(i0+d)*SB + j0] = z;
      }
    }
    __syncthreads();
    // Z = U * C^T: Z[i][j] = sum_k U[i][k] * C[j][k]; offdiag -> global
    {
      float acc[4][2] = {};
      #pragma unroll
      for (int k4 = 0; k4 < 32; k4 += 4) {
        float4 av[4], bv[2];
        #pragma unroll
        for (int d = 0; d < 4; ++d)
          av[d] = *(float4*)&buf2[(i0+d)*SB + k4];
        #pragma unroll
        for (int e = 0; e < 2; ++e)
          bv[e] = *(float4*)&buf0[(j0+e)*SB + k4];
        #pragma unroll
        for (int d = 0; d < 4; ++d)
          #pragma unroll
          for (int e = 0; e < 2; ++e) {
            acc[d][e] = fmaf(av[d].x, bv[e].x, acc[d][e]);
            acc[d][e] = fmaf(av[d].y, bv[e].y, acc[d][e]);
            acc[d][e] = fmaf(av[d].z, bv[e].z, acc[d][e]);
            acc[d][e] = fmaf(av[d].w, bv[e].w, acc[d][e]);
          }
      }
      float ss = 0.0f;
      float* outp = (w == 0) ? qo : ((w == 1) ? ko : vo);
      #pragma unroll
      for (int d = 0; d < 4; ++d) {
        #pragma unroll
        for (int e = 0; e < 2; ++e) {
          if (i0+d == j0+e) acc[d][e] = 0.0f;
          ss = fmaf(acc[d][e], acc[d][e], ss);
        }
        float2 z; z.x = acc[d][0]; z.y = acc[d][1];
        *(float2*)&outp[(size_t)m*NF + (i0+d)*32 + j0] = z;
      }
      if (w < 2) {
        #pragma unroll
        for (int off = 32; off > 0; off >>= 1)
          ss += __shfl_down(ss, off);
        if ((t & 63) == 0) wsum[t >> 6] = ss;
      }
      __syncthreads();   // wsum visible; Z reads of buf0/buf2 done
      if (w < 2 && t == 0)
        ((w == 0) ? q2 : k2)[m] = wsum[0] + wsum[1];
    }
  }
}

// ---------------------------------------------------------------------------
// Kernel C1: G[b,j,i] = <kf[b,j], qf[b,i]> (K=1024), fused scores epilogue.
// ---------------------------------------------------------------------------
__global__ __launch_bounds__(256) void scores_kernel(
    const float* __restrict__ qf, const float* __restrict__ kf,
    const float* __restrict__ q2, const float* __restrict__ k2,
    float* __restrict__ P) {
  __shared__ float Ks[64][17];
  __shared__ float Qs[64][17];
  const int b = blockIdx.z;
  const int j0 = blockIdx.y * 64;
  const int i0 = blockIdx.x * 64;
  const int tx = threadIdx.x & 15, ty = threadIdx.x >> 4;
  const int lrow = threadIdx.x >> 2;
  const int lc4 = (threadIdx.x & 3) * 4;
  float acc[4][4] = {};
  const float* kb = kf + (size_t)(b*NSQ + j0) * NF;
  const float* qb = qf + (size_t)(b*NSQ + i0) * NF;
  for (int f0 = 0; f0 < NF; f0 += 16) {
    float4 kv = *(const float4*)(kb + (size_t)lrow*NF + f0 + lc4);
    float4 qv = *(const float4*)(qb + (size_t)lrow*NF + f0 + lc4);
    Ks[lrow][lc4+0] = kv.x; Ks[lrow][lc4+1] = kv.y; Ks[lrow][lc4+2] = kv.z; Ks[lrow][lc4+3] = kv.w;
    Qs[lrow][lc4+0] = qv.x; Qs[lrow][lc4+1] = qv.y; Qs[lrow][lc4+2] = qv.z; Qs[lrow][lc4+3] = qv.w;
    __syncthreads();
    #pragma unroll
    for (int kk = 0; kk < 16; ++kk) {
      float a0 = Ks[ty*4+0][kk], a1 = Ks[ty*4+1][kk], a2 = Ks[ty*4+2][kk], a3 = Ks[ty*4+3][kk];
      float b0 = Qs[tx*4+0][kk], b1 = Qs[tx*4+1][kk], b2 = Qs[tx*4+2][kk], b3 = Qs[tx*4+3][kk];
      acc[0][0]=fmaf(a0,b0,acc[0][0]); acc[0][1]=fmaf(a0,b1,acc[0][1]);
      acc[0][2]=fmaf(a0,b2,acc[0][2]); acc[0][3]=fmaf(a0,b3,acc[0][3]);
      acc[1][0]=fmaf(a1,b0,acc[1][0]); acc[1][1]=fmaf(a1,b1,acc[1][1]);
      acc[1][2]=fmaf(a1,b2,acc[1][2]); acc[1][3]=fmaf(a1,b3,acc[1][3]);
      acc[2][0]=fmaf(a2,b0,acc[2][0]); acc[2][1]=fmaf(a2,b1,acc[2][1]);
      acc[2][2]=fmaf(a2,b2,acc[2][2]); acc[2][3]=fmaf(a2,b3,acc[2][3]);
      acc[3][0]=fmaf(a3,b0,acc[3][0]); acc[3][1]=fmaf(a3,b1,acc[3][1]);
      acc[3][2]=fmaf(a3,b2,acc[3][2]); acc[3][3]=fmaf(a3,b3,acc[3][3]);
    }
    __syncthreads();
  }
  #pragma unroll
  for (int u = 0; u < 4; ++u) {
    int j = j0 + ty*4 + u;
    float kj = k2[b*NSQ + j];
    #pragma unroll
    for (int vv = 0; vv < 4; ++vv) {
      int i = i0 + tx*4 + vv;
      float d2 = kj + q2[b*NSQ + i] - 2.0f * acc[u][vv];
      float e = sqrtf(fmaxf(d2, 1e-12f));
      float sc = 1.0f / (1.0f + log1pf(e));
      P[(size_t)(b*NSQ + j)*NSQ + i] = sc;
    }
  }
}

// ---------------------------------------------------------------------------
// Kernel C1b: softmax over j (axis -2) for each (b,i) column, in place.
// R11: 256 blocks (16 b x 16 i-chunks of 32) x 512 threads (16 j-groups x
// 32 i-lanes). Fixes R10 structural bug: old grid was 128 blocks on 256 CUs
// (half idle) with 128-load latency chains; now 1 block/CU, 8 waves/CU,
// 32-load chains, 128 B contiguous per load.
// ---------------------------------------------------------------------------
__global__ __launch_bounds__(512) void softmax_kernel(float* __restrict__ P) {
  __shared__ float red[16][32];
  const int b = blockIdx.x >> 4;
  const int i0 = (blockIdx.x & 15) * 32;
  const int il = threadIdx.x & 31;
  const int jg = threadIdx.x >> 5;   // 0..15
  float* base = P + (size_t)b*NSQ*NSQ + i0 + il;
  float mx = -1e30f;
  for (int j = jg*32; j < jg*32 + 32; ++j)
    mx = fmaxf(mx, base[(size_t)j*NSQ]);
  red[jg][il] = mx;
  __syncthreads();
  float cm = red[0][il];
  #pragma unroll
  for (int g = 1; g < 16; ++g) cm = fmaxf(cm, red[g][il]);
  __syncthreads();
  float ssum = 0.0f;
  for (int j = jg*32; j < jg*32 + 32; ++j)
    ssum += expf(base[(size_t)j*NSQ] - cm);
  red[jg][il] = ssum;
  __syncthreads();
  float tot = red[0][il];
  #pragma unroll
  for (int g = 1; g < 16; ++g) tot += red[g][il];
  float inv = 1.0f / tot;
  for (int j = jg*32; j < jg*32 + 32; ++j) {
    size_t o = (size_t)j*NSQ;
    base[o] = expf(base[o] - cm) * inv;
  }
}

// ---------------------------------------------------------------------------
// Kernel C2: out[b,c,f] = sum_a P[b,c,a] * vf[b,a,f]   (NN GEMM, K=512)
// ---------------------------------------------------------------------------
__global__ __launch_bounds__(256) void out_gemm_kernel(
    const float* __restrict__ P, const float* __restrict__ vf,
    float* __restrict__ out) {
  __shared__ float Ps[64][17];
  __shared__ float Vs[16][68];
  const int b = blockIdx.z;
  const int c0 = blockIdx.y * 64;
  const int f0 = blockIdx.x * 64;
  const int tx = threadIdx.x & 15, ty = threadIdx.x >> 4;
  float acc[4][4] = {};
  const float* Pb = P + (size_t)b * NSQ * NSQ;
  const float* Vb = vf + (size_t)b * NSQ * NF;
  for (int a0 = 0; a0 < NSQ; a0 += 16) {
    {
      int row = threadIdx.x >> 2;
      int c4 = (threadIdx.x & 3) * 4;
      float4 pv = *(const float4*)(Pb + (size_t)(c0 + row) * NSQ + a0 + c4);
      Ps[row][c4+0]=pv.x; Ps[row][c4+1]=pv.y; Ps[row][c4+2]=pv.z; Ps[row][c4+3]=pv.w;
    }
    {
      int row = threadIdx.x >> 4;
      int c4 = (threadIdx.x & 15) * 4;
      float4 vv4 = *(const float4*)(Vb + (size_t)(a0 + row) * NF + f0 + c4);
      Vs[row][c4+0]=vv4.x; Vs[row][c4+1]=vv4.y; Vs[row][c4+2]=vv4.z; Vs[row][c4+3]=vv4.w;
    }
    __syncthreads();
    #pragma unroll
    for (int kk = 0; kk < 16; ++kk) {
      float a0r = Ps[ty*4+0][kk], a1r = Ps[ty*4+1][kk], a2r = Ps[ty*4+2][kk], a3r = Ps[ty*4+3][kk];
      float b0 = Vs[kk][tx*4+0], b1 = Vs[kk][tx*4+1], b2 = Vs[kk][tx*4+2], b3 = Vs[kk][tx*4+3];
      acc[0][0]=fmaf(a0r,b0,acc[0][0]); acc[0][1]=fmaf(a0r,b1,acc[0][1]);
      acc[0][2]=fmaf(a0r,b2,acc[0][2]); acc[0][3]=fmaf(a0r,b3,acc[0][3]);
      acc[1][0]=fmaf(a1r,b0,acc[1][0]); acc[1][1]=fmaf(a1r,b1,acc[1][1]);
      acc[1][2]=fmaf(a1r,b2,acc[1][2]); acc[1][3]=fmaf(a1r,b3,acc[1][3]);
      acc[2][0]=fmaf(a2r,b0,acc[2][0]); acc[2][1]=fmaf(a2r,b1,acc[2][1]);
      acc[2][2]=fmaf(a2r,b2,acc[2][2]); acc[2][3]=fmaf(a2r,b3,acc[2][3]);
      acc[3][0]=fmaf(a3r,b0,acc[3][0]); acc[3][1]=fmaf(a3r,b1,acc[3][1]);
      acc[3][2]=fmaf(a3r,b2,acc[3][2]); acc[3][3]=fmaf(a3r,b3,acc[3][3]);
    }
    __syncthreads();
  }
  #pragma unroll
  for (int u = 0; u < 4; ++u) {
    float4 o;
    o.x = acc[u][0]; o.y = acc[u][1]; o.z = acc[u][2]; o.w = acc[u][3];
    *(float4*)(out + (size_t)(b*NSQ + c0 + ty*4 + u) * NF + f0 + tx*4) = o;
  }
}

extern "C" void kernel_launch(void* const* d_in, const int* in_sizes, int n_in,
                              void* d_out, int out_size, void* d_ws, size_t ws_size,
                              hipStream_t stream) {
  const float* x  = (const float*)d_in[0];
  const float* qw = (const float*)d_in[1];
  const float* kw = (const float*)d_in[2];
  const float* vw = (const float*)d_in[3];
  float* ws = (float*)d_ws;
  float* C  = ws;
  float* q  = ws + 3072;
  float* k  = q + (size_t)NMAT * NF;
  float* v  = k + (size_t)NMAT * NF;
  float* q2 = v + (size_t)NMAT * NF;
  float* k2 = q2 + NMAT;
  float* P  = k2 + NMAT;
  float* out = (float*)d_out;

  cayley_kernel<<<dim3(3), dim3(64), 0, stream>>>(qw, kw, vw, C);
  logm_qkv_kernel<<<dim3(NMAT), dim3(128), 0, stream>>>(x, C, q, k, v, q2, k2);
  scores_kernel<<<dim3(8, 8, NB), dim3(256), 0, stream>>>(q, k, q2, k2, P);
  softmax_kernel<<<dim3(NB * 16), dim3(512), 0, stream>>>(P);
  out_gemm_kernel<<<dim3(16, 8, NB), dim3(256), 0, stream>>>(P, v, out);
}

// Round 12
// 1368.725 us; speedup vs baseline: 1.8390x; 1.0399x over previous
//
#include <hip/hip_runtime.h>
#include <math.h>

#define NB 16
#define NSQ 512
#define NMAT (NB*NSQ)   // 8192
#define NF 1024         // 32*32
#define NSWEEP 7        // 6 sweeps FAILS (absmax 0.195); 7 hits the comparison floor.
#define SB 36           // LDS row stride (floats): 144B = multiple of 16 -> b128-aligned rows

// ---------------------------------------------------------------------------
// Kernel A: Cayley maps. C = (I - X)(I + X)^{-1}, X = W - W^T.
// ---------------------------------------------------------------------------
__global__ __launch_bounds__(64) void cayley_kernel(
    const float* __restrict__ qw, const float* __restrict__ kw,
    const float* __restrict__ vw, float* __restrict__ Cout) {
  __shared__ float M[32][33];
  __shared__ float R[32][33];
  __shared__ float fac[32];
  const float* W = (blockIdx.x == 0) ? qw : ((blockIdx.x == 1) ? kw : vw);
  const int t = threadIdx.x;
  for (int idx = t; idx < 1024; idx += 64) {
    int i = idx >> 5, j = idx & 31;
    float xv = W[i*32+j] - W[j*32+i];
    float d = (i == j) ? 1.0f : 0.0f;
    M[i][j] = d - xv;
    R[i][j] = d + xv;
  }
  __syncthreads();
  for (int k = 0; k < 32; ++k) {
    float inv = 1.0f / M[k][k];
    __syncthreads();
    if (t < 32) M[k][t] *= inv; else R[k][t-32] *= inv;
    __syncthreads();
    if (t < 32) fac[t] = M[t][k];
    __syncthreads();
    if (t < 32) {
      float mk = M[k][t];
      for (int i = 0; i < 32; ++i) {
        if (i == k) continue;
        M[i][t] -= fac[i] * mk;
      }
    } else {
      int tc = t - 32;
      float rk = R[k][tc];
      for (int i = 0; i < 32; ++i) {
        if (i == k) continue;
        R[i][tc] -= fac[i] * rk;
      }
    }
    __syncthreads();
  }
  // R = C^T ; store C row-major: C[p][q] = R[q][p]
  for (int idx = t; idx < 1024; idx += 64) {
    int p = idx >> 5, q = idx & 31;
    Cout[blockIdx.x * 1024 + idx] = R[q][p];
  }
}

// ---------------------------------------------------------------------------
// Kernel B: per-matrix sym eigendecomposition (parallel Jacobi, XOR pairing),
// then S = V log(w) V^T (zero diag), then q/k/v = offdiag(C S C^T) + norms.
// TWO waves (128 threads) per matrix (verified R10: VGPR 52, occ 42%,
// VALUBusy 80% — near the sweep loop's VALU-issue ceiling).
// [R8/R9 LESSON: 2-buffer LDS epilogues cost registers and LOSE.]
// A-update: two-phase b128 at r==1 (verified R7); scalar pi-swap 2x2 blocks
// for r>=2. [R4/R5/R6: fused/two-phase r<=3 variants FAILED — do not revisit.]
// ---------------------------------------------------------------------------
__global__ __launch_bounds__(128) void logm_qkv_kernel(
    const float* __restrict__ x, const float* __restrict__ Cm,
    float* __restrict__ qo, float* __restrict__ ko, float* __restrict__ vo,
    float* __restrict__ q2, float* __restrict__ k2) {
  __shared__ __align__(16) float buf0[32*SB];   // A -> Vrow -> (per w) C
  __shared__ __align__(16) float buf1[32*SB];   // Vt -> T (=offdiag S)
  __shared__ __align__(16) float buf2[32*SB];   // U
  __shared__ __align__(16) float2 cs[16];
  __shared__ __align__(16) float lw[32];
  __shared__ float wsum[2];
  const int t = threadIdx.x;
  const int m = blockIdx.x;
  const float* xm = x + (size_t)m * NF;

  // init A = x (stride SB, b128) and Vt = I : 256 float4 tasks, 2/thread
  #pragma unroll
  for (int s = 0; s < 2; ++s) {
    int fi = t + 128*s;              // float4 index 0..255
    int i = fi >> 3, j4 = (fi & 7) << 2;
    float4 xv = *(const float4*)&xm[(size_t)fi*4];
    *(float4*)&buf0[i*SB + j4] = xv;
    float4 iv;
    iv.x = (i == j4+0) ? 1.0f : 0.0f;
    iv.y = (i == j4+1) ? 1.0f : 0.0f;
    iv.z = (i == j4+2) ? 1.0f : 0.0f;
    iv.w = (i == j4+3) ? 1.0f : 0.0f;
    *(float4*)&buf1[i*SB + j4] = iv;
  }
  __syncthreads();

  const int abase = t >> 4;    // row-pair group 0..7
  const int bI = t & 15;       // col-pair index
  const int pi = abase & 1;    // role-swap parity

  for (int sw = 0; sw < NSWEEP; ++sw) {
    for (int r = 1; r < 32; ++r) {
      const int h = 31 - __builtin_clz((unsigned)r);
      const int lowmask = (1 << h) - 1;
      // phase 1: rotation angles for the 16 disjoint pairs {p, p^r}
      if (t < 16) {
        int p = ((t >> h) << (h+1)) | (t & lowmask);
        int q = p ^ r;
        float apq = buf0[p*SB+q];
        float c = 1.0f, s = 0.0f;
        if (fabsf(apq) > 1e-36f) {
          float app = buf0[p*SB+p];
          float aqq = buf0[q*SB+q];
          float tau = (aqq - app) / (2.0f * apq);
          float tt = 1.0f / (fabsf(tau) + sqrtf(1.0f + tau*tau));
          tt = (tau < 0.0f) ? -tt : tt;
          c = 1.0f / sqrtf(1.0f + tt*tt);
          s = tt * c;
        }
        cs[t] = make_float2(c, s);
      }
      __syncthreads();
      if (r == 1) {
        // --- phase A: row rotations B = J^T A (b128); pairs (2k,2k+1);
        //     128 tasks (16 pairs x 8 chunks), 1 per thread ---
        {
          int pr = t >> 3;                 // pair 0..15
          int ch = (t & 7) << 2;           // column chunk
          int p = pr << 1;                 // h=0 -> p = 2*pr
          int q = p | 1;
          float2 c2 = cs[pr];
          float4 ap = *(float4*)&buf0[p*SB + ch];
          float4 aq = *(float4*)&buf0[q*SB + ch];
          float4 np, nq;
          np.x = c2.x*ap.x - c2.y*aq.x;  nq.x = fmaf(c2.y, ap.x, c2.x*aq.x);
          np.y = c2.x*ap.y - c2.y*aq.y;  nq.y = fmaf(c2.y, ap.y, c2.x*aq.y);
          np.z = c2.x*ap.z - c2.y*aq.z;  nq.z = fmaf(c2.y, ap.z, c2.x*aq.z);
          np.w = c2.x*ap.w - c2.y*aq.w;  nq.w = fmaf(c2.y, ap.w, c2.x*aq.w);
          *(float4*)&buf0[p*SB + ch] = np;
          *(float4*)&buf0[q*SB + ch] = nq;
        }
        __syncthreads();   // r is loop-uniform -> all threads reach this
        // --- phase B: col rotations A' = B J, in-register per row-chunk;
        //     local col pairs (0,1) w/ cs[2c] and (2,3) w/ cs[2c+1];
        //     256 tasks, 2 per thread ---
        #pragma unroll
        for (int s4 = 0; s4 < 2; ++s4) {
          int tsk = t + 128*s4;            // 0..255
          int i = tsk >> 3;                // row 0..31
          int cch = tsk & 7;               // chunk 0..7 (cols 4c..4c+3)
          float2 cA = cs[2*cch];
          float2 cB = cs[2*cch+1];
          float4 y = *(float4*)&buf0[i*SB + 4*cch];
          float4 z;
          z.x = cA.x*y.x - cA.y*y.y;  z.y = fmaf(cA.y, y.x, cA.x*y.y);
          z.z = cB.x*y.z - cB.y*y.w;  z.w = fmaf(cB.y, y.z, cB.x*y.w);
          *(float4*)&buf0[i*SB + 4*cch] = z;
        }
      } else {
        // blocked 2x2 scalar update, pi-swapped; 256 blocks, 2 per thread.
        int pb = ((bI >> h) << (h+1)) | (bI & lowmask);
        int qb = pb ^ r;
        if (pi) { int tmp = pb; pb = qb; qb = tmp; }
        const float2 cb2 = cs[bI];
        const float cbb = cb2.x;
        const float sbb = pi ? -cb2.y : cb2.y;
        #pragma unroll
        for (int u = 0; u < 2; ++u) {
          int a = abase + 8*u;
          int pa = ((a >> h) << (h+1)) | (a & lowmask);
          int qa = pa ^ r;
          if (pi) { int tmp = pa; pa = qa; qa = tmp; }
          float2 ca2 = cs[a];
          float caa = ca2.x;
          float saa = pi ? -ca2.y : ca2.y;
          float* rp = buf0 + pa*SB;
          float* rq = buf0 + qa*SB;
          float x11 = rp[pb], x12 = rp[qb];
          float x21 = rq[pb], x22 = rq[qb];
          float y11 = caa*x11 - saa*x21;
          float y12 = caa*x12 - saa*x22;
          float y21 = fmaf(saa, x11, caa*x21);
          float y22 = fmaf(saa, x12, caa*x22);
          rp[pb] = cbb*y11 - sbb*y12;
          rp[qb] = fmaf(sbb, y11, cbb*y12);
          rq[pb] = cbb*y21 - sbb*y22;
          rq[qb] = fmaf(sbb, y21, cbb*y22);
        }
      }
      // V^T row rotations (Vt = J^T Vt), 128 float4 tasks, 1 per thread
      {
        int pr = t >> 3;                 // pair 0..15
        int ch = (t & 7) << 2;           // column chunk
        int p = ((pr >> h) << (h+1)) | (pr & lowmask);
        int q = p ^ r;
        float2 c2 = cs[pr];
        float4 vp = *(float4*)&buf1[p*SB + ch];
        float4 vq = *(float4*)&buf1[q*SB + ch];
        float4 np, nq;
        np.x = c2.x*vp.x - c2.y*vq.x;  nq.x = fmaf(c2.y, vp.x, c2.x*vq.x);
        np.y = c2.x*vp.y - c2.y*vq.y;  nq.y = fmaf(c2.y, vp.y, c2.x*vq.y);
        np.z = c2.x*vp.z - c2.y*vq.z;  nq.z = fmaf(c2.y, vp.z, c2.x*vq.z);
        np.w = c2.x*vp.w - c2.y*vq.w;  nq.w = fmaf(c2.y, vp.w, c2.x*vq.w);
        *(float4*)&buf1[p*SB + ch] = np;
        *(float4*)&buf1[q*SB + ch] = nq;
      }
      __syncthreads();
    }
  }

  if (t < 32) lw[t] = logf(fmaxf(buf0[t*SB+t], 1e-30f));
  __syncthreads();
  // transpose Vt(buf1) -> Vrow(buf0): 1024 scalars, 8 per thread
  #pragma unroll
  for (int s = 0; s < 8; ++s) {
    int idx = t + 128*s;
    int i = idx >> 5, k = idx & 31;
    buf0[i*SB + k] = buf1[k*SB + i];
  }
  __syncthreads();

  // tile partition: 128 threads own 4x2 output tiles (8 row-groups x 16 col-groups)
  const int rg = t >> 4, cg = t & 15;
  const int i0 = rg*4, j0 = cg*2;
  // T = offdiag(S), S[i][j] = sum_k (Vrow[i][k]*lw[k]) * Vrow[j][k]  -> buf1
  {
    float acc[4][2] = {};
    #pragma unroll
    for (int k4 = 0; k4 < 32; k4 += 4) {
      float4 lv = *(float4*)&lw[k4];
      float4 av[4], bv[2];
      #pragma unroll
      for (int d = 0; d < 4; ++d) {
        float4 a4 = *(float4*)&buf0[(i0+d)*SB + k4];
        av[d].x = a4.x*lv.x; av[d].y = a4.y*lv.y; av[d].z = a4.z*lv.z; av[d].w = a4.w*lv.w;
      }
      #pragma unroll
      for (int e = 0; e < 2; ++e)
        bv[e] = *(float4*)&buf0[(j0+e)*SB + k4];
      #pragma unroll
      for (int d = 0; d < 4; ++d)
        #pragma unroll
        for (int e = 0; e < 2; ++e) {
          acc[d][e] = fmaf(av[d].x, bv[e].x, acc[d][e]);
          acc[d][e] = fmaf(av[d].y, bv[e].y, acc[d][e]);
          acc[d][e] = fmaf(av[d].z, bv[e].z, acc[d][e]);
          acc[d][e] = fmaf(av[d].w, bv[e].w, acc[d][e]);
        }
    }
    #pragma unroll
    for (int d = 0; d < 4; ++d) {
      #pragma unroll
      for (int e = 0; e < 2; ++e)
        if (i0+d == j0+e) acc[d][e] = 0.0f;
      float2 z; z.x = acc[d][0]; z.y = acc[d][1];
      *(float2*)&buf1[(i0+d)*SB + j0] = z;
    }
  }
  __syncthreads();

  for (int w = 0; w < 3; ++w) {
    const float* Cw = Cm + w*1024;
    // load C -> buf0 (over dead Vrow), 256 float4, 2 per thread
    #pragma unroll
    for (int s = 0; s < 2; ++s) {
      int fi = t + 128*s;
      int i = fi >> 3, c4 = (fi & 7) << 2;
      *(float4*)&buf0[i*SB + c4] = *(const float4*)&Cw[fi*4];
    }
    __syncthreads();
    // U = C * T (T symmetric): U[i][j] = sum_k C[i][k] * T[j][k] -> buf2
    {
      float acc[4][2] = {};
      #pragma unroll
      for (int k4 = 0; k4 < 32; k4 += 4) {
        float4 av[4], bv[2];
        #pragma unroll
        for (int d = 0; d < 4; ++d)
          av[d] = *(float4*)&buf0[(i0+d)*SB + k4];
        #pragma unroll
        for (int e = 0; e < 2; ++e)
          bv[e] = *(float4*)&buf1[(j0+e)*SB + k4];
        #pragma unroll
        for (int d = 0; d < 4; ++d)
          #pragma unroll
          for (int e = 0; e < 2; ++e) {
            acc[d][e] = fmaf(av[d].x, bv[e].x, acc[d][e]);
            acc[d][e] = fmaf(av[d].y, bv[e].y, acc[d][e]);
            acc[d][e] = fmaf(av[d].z, bv[e].z, acc[d][e]);
            acc[d][e] = fmaf(av[d].w, bv[e].w, acc[d][e]);
          }
      }
      #pragma unroll
      for (int d = 0; d < 4; ++d) {
        float2 z; z.x = acc[d][0]; z.y = acc[d][1];
        *(float2*)&buf2[(i0+d)*SB + j0] = z;
      }
    }
    __syncthreads();
    // Z = U * C^T: Z[i][j] = sum_k U[i][k] * C[j][k]; offdiag -> global
    {
      float acc[4][2] = {};
      #pragma unroll
      for (int k4 = 0; k4 < 32; k4 += 4) {
        float4 av[4], bv[2];
        #pragma unroll
        for (int d = 0; d < 4; ++d)
          av[d] = *(float4*)&buf2[(i0+d)*SB + k4];
        #pragma unroll
        for (int e = 0; e < 2; ++e)
          bv[e] = *(float4*)&buf0[(j0+e)*SB + k4];
        #pragma unroll
        for (int d = 0; d < 4; ++d)
          #pragma unroll
          for (int e = 0; e < 2; ++e) {
            acc[d][e] = fmaf(av[d].x, bv[e].x, acc[d][e]);
            acc[d][e] = fmaf(av[d].y, bv[e].y, acc[d][e]);
            acc[d][e] = fmaf(av[d].z, bv[e].z, acc[d][e]);
            acc[d][e] = fmaf(av[d].w, bv[e].w, acc[d][e]);
          }
      }
      float ss = 0.0f;
      float* outp = (w == 0) ? qo : ((w == 1) ? ko : vo);
      #pragma unroll
      for (int d = 0; d < 4; ++d) {
        #pragma unroll
        for (int e = 0; e < 2; ++e) {
          if (i0+d == j0+e) acc[d][e] = 0.0f;
          ss = fmaf(acc[d][e], acc[d][e], ss);
        }
        float2 z; z.x = acc[d][0]; z.y = acc[d][1];
        *(float2*)&outp[(size_t)m*NF + (i0+d)*32 + j0] = z;
      }
      if (w < 2) {
        #pragma unroll
        for (int off = 32; off > 0; off >>= 1)
          ss += __shfl_down(ss, off);
        if ((t & 63) == 0) wsum[t >> 6] = ss;
      }
      __syncthreads();   // wsum visible; Z reads of buf0/buf2 done
      if (w < 2 && t == 0)
        ((w == 0) ? q2 : k2)[m] = wsum[0] + wsum[1];
    }
  }
}

// ---------------------------------------------------------------------------
// Kernel C1: G[b,j,i] = <kf[b,j], qf[b,i]> (K=1024), fused scores epilogue.
// R12: 128x128 tile, 256 threads, 8x8 micro-tile, K-major (transposed)
// staging -> inner loop is 4 broadcast ds_read_b128 vs 64 fma (compute-bound;
// old 64-tile/4x4 was 16 scalar ds_read per 32 fma -> LDS-bound, ~40% peak).
// Same K-accumulation order per element -> bit-identical output.
// ---------------------------------------------------------------------------
__global__ __launch_bounds__(256) void scores_kernel(
    const float* __restrict__ qf, const float* __restrict__ kf,
    const float* __restrict__ q2, const float* __restrict__ k2,
    float* __restrict__ P) {
  __shared__ float Ks[16][132];   // [k][j] transposed
  __shared__ float Qs[16][132];   // [k][i] transposed
  const int b = blockIdx.z;
  const int j0 = blockIdx.y * 128;
  const int i0 = blockIdx.x * 128;
  const int tx = threadIdx.x & 15, ty = threadIdx.x >> 4;  // i-group, j-group
  const int srow = threadIdx.x >> 1;        // staging row 0..127
  const int sk8  = (threadIdx.x & 1) * 8;   // staging k-offset 0 or 8
  float acc[8][8] = {};
  const float* kb = kf + (size_t)(b*NSQ + j0) * NF;
  const float* qb = qf + (size_t)(b*NSQ + i0) * NF;
  for (int f0 = 0; f0 < NF; f0 += 16) {
    float4 ka = *(const float4*)(kb + (size_t)srow*NF + f0 + sk8);
    float4 kb4 = *(const float4*)(kb + (size_t)srow*NF + f0 + sk8 + 4);
    float4 qa = *(const float4*)(qb + (size_t)srow*NF + f0 + sk8);
    float4 qb4 = *(const float4*)(qb + (size_t)srow*NF + f0 + sk8 + 4);
    __syncthreads();   // prev iteration's reads done before overwrite
    Ks[sk8+0][srow] = ka.x;  Ks[sk8+1][srow] = ka.y;
    Ks[sk8+2][srow] = ka.z;  Ks[sk8+3][srow] = ka.w;
    Ks[sk8+4][srow] = kb4.x; Ks[sk8+5][srow] = kb4.y;
    Ks[sk8+6][srow] = kb4.z; Ks[sk8+7][srow] = kb4.w;
    Qs[sk8+0][srow] = qa.x;  Qs[sk8+1][srow] = qa.y;
    Qs[sk8+2][srow] = qa.z;  Qs[sk8+3][srow] = qa.w;
    Qs[sk8+4][srow] = qb4.x; Qs[sk8+5][srow] = qb4.y;
    Qs[sk8+6][srow] = qb4.z; Qs[sk8+7][srow] = qb4.w;
    __syncthreads();
    #pragma unroll
    for (int kk = 0; kk < 16; ++kk) {
      float4 a0 = *(float4*)&Ks[kk][ty*8];
      float4 a1 = *(float4*)&Ks[kk][ty*8 + 4];
      float4 b0 = *(float4*)&Qs[kk][tx*8];
      float4 b1 = *(float4*)&Qs[kk][tx*8 + 4];
      float av[8] = {a0.x,a0.y,a0.z,a0.w,a1.x,a1.y,a1.z,a1.w};
      float bv[8] = {b0.x,b0.y,b0.z,b0.w,b1.x,b1.y,b1.z,b1.w};
      #pragma unroll
      for (int d = 0; d < 8; ++d)
        #pragma unroll
        for (int e = 0; e < 8; ++e)
          acc[d][e] = fmaf(av[d], bv[e], acc[d][e]);
    }
  }
  #pragma unroll
  for (int u = 0; u < 8; ++u) {
    int j = j0 + ty*8 + u;
    float kj = k2[b*NSQ + j];
    float* prow = P + (size_t)(b*NSQ + j)*NSQ + i0 + tx*8;
    #pragma unroll
    for (int vv = 0; vv < 8; ++vv) {
      int i = i0 + tx*8 + vv;
      float d2 = kj + q2[b*NSQ + i] - 2.0f * acc[u][vv];
      float e = sqrtf(fmaxf(d2, 1e-12f));
      prow[vv] = 1.0f / (1.0f + log1pf(e));
    }
  }
}

// ---------------------------------------------------------------------------
// Kernel C1b: softmax over j (axis -2) for each (b,i) column, in place.
// R11: 256 blocks x 512 threads, 1 block/CU, 32-load chains.
// ---------------------------------------------------------------------------
__global__ __launch_bounds__(512) void softmax_kernel(float* __restrict__ P) {
  __shared__ float red[16][32];
  const int b = blockIdx.x >> 4;
  const int i0 = (blockIdx.x & 15) * 32;
  const int il = threadIdx.x & 31;
  const int jg = threadIdx.x >> 5;   // 0..15
  float* base = P + (size_t)b*NSQ*NSQ + i0 + il;
  float mx = -1e30f;
  for (int j = jg*32; j < jg*32 + 32; ++j)
    mx = fmaxf(mx, base[(size_t)j*NSQ]);
  red[jg][il] = mx;
  __syncthreads();
  float cm = red[0][il];
  #pragma unroll
  for (int g = 1; g < 16; ++g) cm = fmaxf(cm, red[g][il]);
  __syncthreads();
  float ssum = 0.0f;
  for (int j = jg*32; j < jg*32 + 32; ++j)
    ssum += expf(base[(size_t)j*NSQ] - cm);
  red[jg][il] = ssum;
  __syncthreads();
  float tot = red[0][il];
  #pragma unroll
  for (int g = 1; g < 16; ++g) tot += red[g][il];
  float inv = 1.0f / tot;
  for (int j = jg*32; j < jg*32 + 32; ++j) {
    size_t o = (size_t)j*NSQ;
    base[o] = expf(base[o] - cm) * inv;
  }
}

// ---------------------------------------------------------------------------
// Kernel C2: out[b,c,f] = sum_a P[b,c,a] * vf[b,a,f]   (NN GEMM, K=512)
// R12: 128x128 tile, 256 threads, 8x8 micro, Ps staged K-major (transposed),
// Vs staged row-major (already K-major in f). Bit-identical accumulation.
// ---------------------------------------------------------------------------
__global__ __launch_bounds__(256) void out_gemm_kernel(
    const float* __restrict__ P, const float* __restrict__ vf,
    float* __restrict__ out) {
  __shared__ float Ps[16][132];   // [a][c] transposed
  __shared__ float Vs[16][132];   // [a][f]
  const int b = blockIdx.z;
  const int c0 = blockIdx.y * 128;
  const int f0 = blockIdx.x * 128;
  const int tx = threadIdx.x & 15, ty = threadIdx.x >> 4;  // f-group, c-group
  const int srow = threadIdx.x >> 1;        // P staging row (c) 0..127
  const int sk8  = (threadIdx.x & 1) * 8;   // P staging a-offset 0 or 8
  const int vrow = threadIdx.x >> 4;        // V staging row (a) 0..15
  const int vc8  = (threadIdx.x & 15) * 8;  // V staging f-offset
  float acc[8][8] = {};
  const float* Pb = P + (size_t)b * NSQ * NSQ;
  const float* Vb = vf + (size_t)b * NSQ * NF;
  for (int a0 = 0; a0 < NSQ; a0 += 16) {
    float4 pa = *(const float4*)(Pb + (size_t)(c0 + srow)*NSQ + a0 + sk8);
    float4 pb4 = *(const float4*)(Pb + (size_t)(c0 + srow)*NSQ + a0 + sk8 + 4);
    float4 va = *(const float4*)(Vb + (size_t)(a0 + vrow)*NF + f0 + vc8);
    float4 vb4 = *(const float4*)(Vb + (size_t)(a0 + vrow)*NF + f0 + vc8 + 4);
    __syncthreads();
    Ps[sk8+0][srow] = pa.x;  Ps[sk8+1][srow] = pa.y;
    Ps[sk8+2][srow] = pa.z;  Ps[sk8+3][srow] = pa.w;
    Ps[sk8+4][srow] = pb4.x; Ps[sk8+5][srow] = pb4.y;
    Ps[sk8+6][srow] = pb4.z; Ps[sk8+7][srow] = pb4.w;
    *(float4*)&Vs[vrow][vc8] = va;
    *(float4*)&Vs[vrow][vc8 + 4] = vb4;
    __syncthreads();
    #pragma unroll
    for (int kk = 0; kk < 16; ++kk) {
      float4 a0v = *(float4*)&Ps[kk][ty*8];
      float4 a1v = *(float4*)&Ps[kk][ty*8 + 4];
      float4 b0v = *(float4*)&Vs[kk][tx*8];
      float4 b1v = *(float4*)&Vs[kk][tx*8 + 4];
      float av[8] = {a0v.x,a0v.y,a0v.z,a0v.w,a1v.x,a1v.y,a1v.z,a1v.w};
      float bv[8] = {b0v.x,b0v.y,b0v.z,b0v.w,b1v.x,b1v.y,b1v.z,b1v.w};
      #pragma unroll
      for (int d = 0; d < 8; ++d)
        #pragma unroll
        for (int e = 0; e < 8; ++e)
          acc[d][e] = fmaf(av[d], bv[e], acc[d][e]);
    }
  }
  #pragma unroll
  for (int u = 0; u < 8; ++u) {
    float* orow = out + (size_t)(b*NSQ + c0 + ty*8 + u) * NF + f0 + tx*8;
    float4 o0; o0.x = acc[u][0]; o0.y = acc[u][1]; o0.z = acc[u][2]; o0.w = acc[u][3];
    float4 o1; o1.x = acc[u][4]; o1.y = acc[u][5]; o1.z = acc[u][6]; o1.w = acc[u][7];
    *(float4*)orow = o0;
    *(float4*)(orow + 4) = o1;
  }
}

extern "C" void kernel_launch(void* const* d_in, const int* in_sizes, int n_in,
                              void* d_out, int out_size, void* d_ws, size_t ws_size,
                              hipStream_t stream) {
  const float* x  = (const float*)d_in[0];
  const float* qw = (const float*)d_in[1];
  const float* kw = (const float*)d_in[2];
  const float* vw = (const float*)d_in[3];
  float* ws = (float*)d_ws;
  float* C  = ws;
  float* q  = ws + 3072;
  float* k  = q + (size_t)NMAT * NF;
  float* v  = k + (size_t)NMAT * NF;
  float* q2 = v + (size_t)NMAT * NF;
  float* k2 = q2 + NMAT;
  float* P  = k2 + NMAT;
  float* out = (float*)d_out;

  cayley_kernel<<<dim3(3), dim3(64), 0, stream>>>(qw, kw, vw, C);
  logm_qkv_kernel<<<dim3(NMAT), dim3(128), 0, stream>>>(x, C, q, k, v, q2, k2);
  scores_kernel<<<dim3(4, 4, NB), dim3(256), 0, stream>>>(q, k, q2, k2, P);
  softmax_kernel<<<dim3(NB * 16), dim3(512), 0, stream>>>(P);
  out_gemm_kernel<<<dim3(8, 4, NB), dim3(256), 0, stream>>>(P, v, out);
}